// Round 3
// baseline (1019.955 us; speedup 1.0000x reference)
//
#include <hip/hip_runtime.h>

// GraphTripleConvNet, fully linear -> aggressive weight composition.
// Round 6: double-buffered GLDS pipeline in gemm64_k — issue next K-tile's
// global_load_lds BEFORE computing the current tile, ONE barrier per K-step
// (was: sync; GLDS; sync = full HBM latency exposed every iteration).
// LDS 16->32KB (5 blocks/CU). Everything else unchanged from round 5b.
//
// Per layer:
//   pool_t : tSO[o] = [ns*obj|SUMs pred|SUMs obj[o']|SUMo obj[s']|SUMo pred|no*obj]
//   GEMM_A : new_obj = (tSO @ (W12so@W34) + ns*c1' + no*c2')/max(deg,1) + b34   (K=1536,N=256)
//   GEMM_C : objSO   = obj @ [Wp_s|Wp_o]                                        (K=256, N=512)
//   GEMM_B : new_pred[e] = pred@Wp_p + b12p + objSO[s_e][0:256] + objSO[o_e][256:512]  (fused)

#define NTRI 60000
#define NOBJ 20000
#define DD 256
#define HH 512

typedef __attribute__((ext_vector_type(8))) short bf16x8;
typedef __attribute__((ext_vector_type(4))) float f32x4;

#define GLDS(gp, lp) __builtin_amdgcn_global_load_lds( \
    (const __attribute__((address_space(1))) void*)(gp), \
    (__attribute__((address_space(3))) void*)(lp), 16, 0, 0)

__device__ __forceinline__ unsigned short f2bf(float f){
  unsigned int x = __builtin_bit_cast(unsigned int, f);
  x += 0x7fffu + ((x >> 16) & 1u);   // RNE
  return (unsigned short)(x >> 16);
}
__device__ __forceinline__ float bf2f(unsigned short u){
  return __builtin_bit_cast(float, (unsigned int)u << 16);
}

// ---------------------------------------------------------------------------
// C(MxN) = A(MxK,bf16) @ Bt(NxK,bf16)^T [+ epilogue].  64x64 tile, BK=64,
// 4 waves (2x2 wave grid), each wave 2x2 frags of mfma_f32_16x16x32_bf16.
// K % 64 == 0, N % 64 == 0; M guarded.  grid.z batching via strides (elements).
// Double-buffered LDS pipeline: prologue stages tile 0; each iteration issues
// GLDS for tile t+1 into buf^1, computes tile t from buf, then ONE barrier
// (compiler's vmcnt(0)+lgkmcnt(0) drain before s_barrier makes buf^1 ready and
// all LDS reads of buf complete).  HBM latency overlaps ds_read+MFMA.
// LDS layout XOR-swizzled: chunk(row,k16) at row*8 + (k16 ^ (row&7)); GLDS dest
// linear, global source kp carries the inverse permutation (both-sides rule).
// MODE 0: bf16 + bias[col].
// MODE 2: bf16, v = (acc + ns*bias + no*bias2)/max(ns+no,1) + bias3.
// MODE 6: fp32, same epilogue as MODE 2.
// MODE 3: bf16 transposed store out[col*ldT+row] (weight composition).
// MODE 5: bf16, no bias.
// MODE 7: bf16, v = acc + bias[col] + gath[s_e][col] + gath[o_e][256+col].
// MODE 8: fp32, same epilogue as MODE 7.
// ---------------------------------------------------------------------------
template<int MODE>
__global__ __launch_bounds__(256) void gemm64_k(
    const unsigned short* __restrict__ A,
    const unsigned short* __restrict__ Bt,
    const float* __restrict__ bias,
    const float* __restrict__ bias2,
    const float* __restrict__ bias3,
    const int* __restrict__ cntS,
    const int* __restrict__ cntO,
    const int2* __restrict__ eidx,
    const unsigned short* __restrict__ gath,
    void* __restrict__ out0,
    int M, int K, int N, int ldT,
    long strideA, long strideB, long strideC)
{
  __shared__ unsigned short sA[2][64*64];
  __shared__ unsigned short sB[2][64*64];
  const int tid  = threadIdx.x;
  const int lane = tid & 63;
  const int wv   = tid >> 6;
  const int wm   = wv & 1;
  const int wn   = wv >> 1;
  const int quad = lane >> 4;
  const int l15  = lane & 15;

  // bijective XCD-chunked swizzle (m204): consecutive logical blocks (the
  // n-tiles sharing an A-row panel) land on the SAME XCD -> A reread = L2 hit.
  const int nxy = gridDim.x * gridDim.y;
  int bid = blockIdx.y * gridDim.x + blockIdx.x;
  {
    const int q = nxy >> 3, r = nxy & 7;
    const int x = bid & 7, i = bid >> 3;
    bid = (x < r ? x * (q + 1) : r * (q + 1) + (x - r) * q) + i;
  }
  const int m0 = (bid / gridDim.x) * 64;
  const int n0 = (bid % gridDim.x) * 64;
  const size_t zb = blockIdx.z;
  A  += zb * strideA;
  Bt += zb * strideB;

  f32x4 acc[2][2] = {};

  const int rr = tid >> 3;                               // staging row 0..31
  const int kp = (((tid & 7) ^ (rr & 7)) << 3);          // pre-swizzled k chunk
  const int r0 = m0 + rr;
  const int r1 = r0 + 32;                                // (r1&7)==(r0&7): same kp
  const int ra0 = (r0 < M) ? r0 : (M - 1);               // clamped; stores guarded
  const int ra1 = (r1 < M) ? r1 : (M - 1);
  const unsigned short* gA0 = A + (size_t)ra0 * K + kp;
  const unsigned short* gA1 = A + (size_t)ra1 * K + kp;
  const unsigned short* gB0 = Bt + (size_t)(n0 + rr) * K + kp;
  const unsigned short* gB1 = Bt + (size_t)(n0 + 32 + rr) * K + kp;

  const int swq = lane & 7;                              // == frag_row & 7
  const int t8  = tid * 8;

  // ---- prologue: stage tile 0 into buf 0 ----
  GLDS(gA0, sA[0] + t8); GLDS(gA1, sA[0] + t8 + 2048);
  GLDS(gB0, sB[0] + t8); GLDS(gB1, sB[0] + t8 + 2048);
  gA0 += 64; gA1 += 64; gB0 += 64; gB1 += 64;
  __syncthreads();                                       // vmcnt(0) drain: buf0 ready

  const int nt = K >> 6;
  int cur = 0;
  for (int t = 0; t < nt; ++t){
    if (t + 1 < nt){                                     // issue next tile first
      GLDS(gA0, sA[cur ^ 1] + t8); GLDS(gA1, sA[cur ^ 1] + t8 + 2048);
      GLDS(gB0, sB[cur ^ 1] + t8); GLDS(gB1, sB[cur ^ 1] + t8 + 2048);
      gA0 += 64; gA1 += 64; gB0 += 64; gB1 += 64;
    }
    bf16x8 af[2][2], bq[2][2];
#pragma unroll
    for (int kc = 0; kc < 2; ++kc){
      const int sw = (((kc * 4 + quad) ^ swq) << 3);     // swizzled read offset
#pragma unroll
      for (int mt = 0; mt < 2; ++mt)
        af[kc][mt] = *(const bf16x8*)(sA[cur] + (wm*32 + mt*16 + l15)*64 + sw);
#pragma unroll
      for (int nt2 = 0; nt2 < 2; ++nt2)
        bq[kc][nt2] = *(const bf16x8*)(sB[cur] + (wn*32 + nt2*16 + l15)*64 + sw);
    }
#pragma unroll
    for (int kc = 0; kc < 2; ++kc)
#pragma unroll
      for (int mt = 0; mt < 2; ++mt)
#pragma unroll
        for (int nt2 = 0; nt2 < 2; ++nt2)
          acc[mt][nt2] = __builtin_amdgcn_mfma_f32_16x16x32_bf16(af[kc][mt], bq[kc][nt2], acc[mt][nt2], 0, 0, 0);
    __syncthreads();                                     // drains vmcnt (next buf ready) + lgkm
    cur ^= 1;
  }

  // C/D layout: col = l15, row = quad*4 + reg   [m89-verified]
  if constexpr (MODE == 3){
    unsigned short* outp = (unsigned short*)out0 + zb * strideC;
#pragma unroll
    for (int mt = 0; mt < 2; ++mt){
      const int rb = m0 + wm*32 + mt*16 + quad*4;
#pragma unroll
      for (int nt2 = 0; nt2 < 2; ++nt2){
        const int col = n0 + wn*32 + nt2*16 + l15;
        ushort4 r4;
        r4.x = f2bf(acc[mt][nt2][0]); r4.y = f2bf(acc[mt][nt2][1]);
        r4.z = f2bf(acc[mt][nt2][2]); r4.w = f2bf(acc[mt][nt2][3]);
        *(ushort4*)(outp + (size_t)col * ldT + rb) = r4;
      }
    }
  } else if constexpr (MODE == 7 || MODE == 8){
#pragma unroll
    for (int mt = 0; mt < 2; ++mt){
      const int rb = m0 + wm*32 + mt*16 + quad*4;
#pragma unroll
      for (int r = 0; r < 4; ++r){
        const int row = rb + r;
        if (row >= M) continue;
        const int2 ei = eidx[row];
        const unsigned short* srow = gath + (size_t)ei.x * 512;
        const unsigned short* orow = gath + (size_t)ei.y * 512 + 256;
#pragma unroll
        for (int nt2 = 0; nt2 < 2; ++nt2){
          const int col = n0 + wn*32 + nt2*16 + l15;
          const float v = acc[mt][nt2][r] + bias[col] + bf2f(srow[col]) + bf2f(orow[col]);
          if constexpr (MODE == 8) ((float*)out0)[(size_t)row * N + col] = v;
          else ((unsigned short*)out0)[(size_t)row * N + col] = f2bf(v);
        }
      }
    }
  } else {
    char* outp = (char*)out0 + zb * strideC * ((MODE == 6) ? 4 : 2);
#pragma unroll
    for (int mt = 0; mt < 2; ++mt){
      const int rb = m0 + wm*32 + mt*16 + quad*4;
#pragma unroll
      for (int nt2 = 0; nt2 < 2; ++nt2){
        const int col = n0 + wn*32 + nt2*16 + l15;
#pragma unroll
        for (int r = 0; r < 4; ++r){
          const int row = rb + r;
          if (row >= M) continue;
          float v = acc[mt][nt2][r];
          if constexpr (MODE == 0) v += bias[col];
          if constexpr (MODE == 2 || MODE == 6){
            const float ns = (float)cntS[row], no = (float)cntO[row];
            v = (v + ns * bias[col] + no * bias2[col]) / fmaxf(ns + no, 1.f) + bias3[col];
          }
          if constexpr (MODE == 6) ((float*)outp)[(size_t)row * N + col] = v;
          else                     ((unsigned short*)outp)[(size_t)row * N + col] = f2bf(v);
        }
      }
    }
  }
}

// --- edges dtype autodetect ---
__global__ __launch_bounds__(256) void detect_k(const int* __restrict__ e, int* __restrict__ flag)
{
  const int i = blockIdx.x * 256 + threadIdx.x;
  if (i >= NTRI) return;
  if (e[2*i + 1] != 0) atomicOr(flag, 1);   // any nonzero odd word => int32 layout
}

__global__ __launch_bounds__(256) void norm_k(const int* __restrict__ e, const int* __restrict__ flag,
                                              int2* __restrict__ eidx)
{
  const int i = blockIdx.x * 256 + threadIdx.x;
  if (i >= NTRI) return;
  int s, o;
  if (*flag){ s = e[2*i]; o = e[2*i + 1]; }
  else      { s = e[4*i]; o = e[4*i + 2]; }
  s = min(max(s, 0), NOBJ - 1);
  o = min(max(o, 0), NOBJ - 1);
  eidx[i] = make_int2(s, o);
}

__global__ __launch_bounds__(256) void deg_k(const int2* __restrict__ eidx,
                                             int* __restrict__ cnt_s, int* __restrict__ cnt_o)
{
  const int i = blockIdx.x * 256 + threadIdx.x;
  if (i >= NTRI) return;
  atomicAdd(&cnt_s[eidx[i].x], 1);
  atomicAdd(&cnt_o[eidx[i].y], 1);
}

__global__ __launch_bounds__(1024) void scan_k(const int* __restrict__ cnt_s,
                                               const int* __restrict__ cnt_o,
                                               int* __restrict__ offs)
{
  __shared__ int sd[1024];
  __shared__ int carry;
  if (threadIdx.x == 0) carry = 0;
  __syncthreads();
  const int nIter = (NOBJ + 1023) / 1024;
  for (int it = 0; it < nIter; ++it){
    const int i = it * 1024 + (int)threadIdx.x;
    const int v = (i < NOBJ) ? (cnt_s[i] + cnt_o[i]) : 0;
    sd[threadIdx.x] = v;
    __syncthreads();
    for (int off = 1; off < 1024; off <<= 1){
      const int t = ((int)threadIdx.x >= off) ? sd[threadIdx.x - off] : 0;
      __syncthreads();
      sd[threadIdx.x] += t;
      __syncthreads();
    }
    if (i < NOBJ) offs[i] = carry + sd[threadIdx.x] - v;
    __syncthreads();
    if (threadIdx.x == 0){
      carry += sd[1023];
      if (it == nIter - 1) offs[NOBJ] = carry;
    }
    __syncthreads();
  }
}

// slot payload: (2*e+role, other_object_index)
__global__ __launch_bounds__(256) void fill_k(const int2* __restrict__ eidx,
                                              int* __restrict__ cursor, int2* __restrict__ slots)
{
  const int i = blockIdx.x * 256 + threadIdx.x;
  if (i >= NTRI) return;
  const int2 e = eidx[i];
  slots[atomicAdd(&cursor[e.x], 1)] = make_int2(2*i,     e.y);   // subject role
  slots[atomicAdd(&cursor[e.y], 1)] = make_int2(2*i + 1, e.x);   // object role
}

// tSO[o][1536] = [ns*obj[o] | SUMs pred | SUMs obj[oidx] | SUMo obj[sidx] | SUMo pred | no*obj[o]]
// v2: ushort4 loads (8B/lane), 4 slot-groups in parallel, LDS tree-combine.
__global__ __launch_bounds__(256) void pool_t_k(
    const unsigned short* __restrict__ obj, const unsigned short* __restrict__ pred,
    const int* __restrict__ offs, const int2* __restrict__ slots,
    const int* __restrict__ cnt_s, const int* __restrict__ cnt_o,
    unsigned short* __restrict__ tSO)
{
  __shared__ __align__(16) float red[4][4][256];   // [group][sum][ch] 16KB
  const int o    = blockIdx.x;
  const int tid  = (int)threadIdx.x;
  const int g    = tid >> 6;
  const int lane = tid & 63;
  const int c4   = lane << 2;
  const int b0 = offs[o], b1 = offs[o + 1];
  float sp0=0.f, sp1=0.f, sp2=0.f, sp3=0.f;
  float so0=0.f, so1=0.f, so2=0.f, so3=0.f;
  float oo0=0.f, oo1=0.f, oo2=0.f, oo3=0.f;
  float op0=0.f, op1=0.f, op2=0.f, op3=0.f;
  for (int j = b0 + g; j < b1; j += 4){
    const int2 sl = slots[j];
    const ushort4 pv = *(const ushort4*)(pred + (size_t)(sl.x >> 1) * DD + c4);
    const ushort4 ov = *(const ushort4*)(obj  + (size_t)sl.y * DD + c4);
    const float p0 = bf2f(pv.x), p1 = bf2f(pv.y), p2 = bf2f(pv.z), p3 = bf2f(pv.w);
    const float q0 = bf2f(ov.x), q1 = bf2f(ov.y), q2 = bf2f(ov.z), q3 = bf2f(ov.w);
    if (sl.x & 1){ op0+=p0; op1+=p1; op2+=p2; op3+=p3; oo0+=q0; oo1+=q1; oo2+=q2; oo3+=q3; }
    else         { sp0+=p0; sp1+=p1; sp2+=p2; sp3+=p3; so0+=q0; so1+=q1; so2+=q2; so3+=q3; }
  }
  red[g][0][c4+0]=sp0; red[g][0][c4+1]=sp1; red[g][0][c4+2]=sp2; red[g][0][c4+3]=sp3;
  red[g][1][c4+0]=so0; red[g][1][c4+1]=so1; red[g][1][c4+2]=so2; red[g][1][c4+3]=so3;
  red[g][2][c4+0]=oo0; red[g][2][c4+1]=oo1; red[g][2][c4+2]=oo2; red[g][2][c4+3]=oo3;
  red[g][3][c4+0]=op0; red[g][3][c4+1]=op1; red[g][3][c4+2]=op2; red[g][3][c4+3]=op3;
  __syncthreads();
  unsigned short* dst = tSO + (size_t)o * 1536;
#define TOTW(s, off) { \
    const float4 t0 = *(const float4*)&red[0][s][c4]; \
    const float4 t1 = *(const float4*)&red[1][s][c4]; \
    const float4 t2 = *(const float4*)&red[2][s][c4]; \
    const float4 t3 = *(const float4*)&red[3][s][c4]; \
    ushort4 w; \
    w.x = f2bf(t0.x + t1.x + t2.x + t3.x); \
    w.y = f2bf(t0.y + t1.y + t2.y + t3.y); \
    w.z = f2bf(t0.z + t1.z + t2.z + t3.z); \
    w.w = f2bf(t0.w + t1.w + t2.w + t3.w); \
    *(ushort4*)(dst + (off) + c4) = w; }
  if (g == 0){
    const ushort4 ob = *(const ushort4*)(obj + (size_t)o * DD + c4);
    const float ns = (float)cnt_s[o];
    ushort4 w;
    w.x = f2bf(ns * bf2f(ob.x)); w.y = f2bf(ns * bf2f(ob.y));
    w.z = f2bf(ns * bf2f(ob.z)); w.w = f2bf(ns * bf2f(ob.w));
    *(ushort4*)(dst + c4) = w;
    TOTW(0, 256);
  } else if (g == 1){
    TOTW(1, 512);
  } else if (g == 2){
    TOTW(2, 768);
    const ushort4 ob = *(const ushort4*)(obj + (size_t)o * DD + c4);
    const float no = (float)cnt_o[o];
    ushort4 w;
    w.x = f2bf(no * bf2f(ob.x)); w.y = f2bf(no * bf2f(ob.y));
    w.z = f2bf(no * bf2f(ob.z)); w.w = f2bf(no * bf2f(ob.w));
    *(ushort4*)(dst + 1280 + c4) = w;
  } else {
    TOTW(3, 1024);
  }
#undef TOTW
}

// fallback path only: new_pred[e][c] = predP[e][c] + objSO[s_e][c] + objSO[o_e][256+c]
template<int OUT>
__global__ __launch_bounds__(256) void add_k(
    const unsigned short* __restrict__ predP, const unsigned short* __restrict__ objSO,
    const int2* __restrict__ eidx, void* __restrict__ outp)
{
  const int i = blockIdx.x * 256 + threadIdx.x;
  if (i >= NTRI * 64) return;
  const int e  = i >> 6;
  const int c4 = (i & 63) << 2;
  const int2 ei = eidx[e];
  const ushort4 a = *(const ushort4*)(predP + (size_t)e * DD + c4);
  const ushort4 s = *(const ushort4*)(objSO + (size_t)ei.x * 512 + c4);
  const ushort4 o = *(const ushort4*)(objSO + (size_t)ei.y * 512 + 256 + c4);
  float v0 = bf2f(a.x) + bf2f(s.x) + bf2f(o.x);
  float v1 = bf2f(a.y) + bf2f(s.y) + bf2f(o.y);
  float v2 = bf2f(a.z) + bf2f(s.z) + bf2f(o.z);
  float v3 = bf2f(a.w) + bf2f(s.w) + bf2f(o.w);
  if constexpr (OUT){
    float4 r = make_float4(v0, v1, v2, v3);
    *(float4*)((float*)outp + (size_t)e * DD + c4) = r;
  } else {
    ushort4 r;
    r.x = f2bf(v0); r.y = f2bf(v1); r.z = f2bf(v2); r.w = f2bf(v3);
    *(ushort4*)((unsigned short*)outp + (size_t)e * DD + c4) = r;
  }
}

// fp32 -> bf16 flat (vector x4)
__global__ __launch_bounds__(256) void conv_f2b_k(const float* __restrict__ x,
                                                  unsigned short* __restrict__ y, int n4)
{
  const int i = blockIdx.x * 256 + threadIdx.x;
  if (i >= n4) return;
  const float4 v = ((const float4*)x)[i];
  ushort4 r;
  r.x = f2bf(v.x); r.y = f2bf(v.y); r.z = f2bf(v.z); r.w = f2bf(v.w);
  ((ushort4*)y)[i] = r;
}

// batched (L=5) transpose-convert: Wt[l][n][k] = bf16(W[l][k][colOff+n]), K=512
__global__ __launch_bounds__(256) void conv_wT_k(
    const float* __restrict__ W, unsigned short* __restrict__ Wt,
    int N, int ldW, int colOff, long wLS, long oLS)
{
  const int idx = blockIdx.x * 256 + threadIdx.x;
  const int per = N * 512;
  if (idx >= 5 * per) return;
  const int l = idx / per;
  const int r = idx - l * per;
  const int n = r >> 9;
  const int k = r & 511;
  Wt[l * oLS + (size_t)n * 512 + k] = f2bf(W[l * wLS + (size_t)k * ldW + colOff + n]);
}

// cb2[l][0..1280) = b1[l]@W2[l] + b2[l];  b34c[l][0..256) = b3[l]@W4[l] + b4[l]
__global__ __launch_bounds__(256) void biascomp_k(
    const float* __restrict__ b1, const float* __restrict__ W2, const float* __restrict__ b2,
    const float* __restrict__ b3, const float* __restrict__ W4, const float* __restrict__ b4,
    float* __restrict__ cb2, float* __restrict__ b34c)
{
  const int idx = blockIdx.x * 256 + threadIdx.x;
  if (idx < 5 * 1280){
    const int l = idx / 1280, n = idx - l * 1280;
    float s = b2[l * 1280 + n];
    for (int k = 0; k < 512; ++k)
      s += b1[l * 512 + k] * W2[(size_t)l * 512 * 1280 + (size_t)k * 1280 + n];
    cb2[idx] = s;
  } else if (idx < 5 * 1280 + 5 * 256){
    const int j = idx - 6400;
    const int l = j / 256, n = j - l * 256;
    float s = b4[l * 256 + n];
    for (int k = 0; k < 512; ++k)
      s += b3[l * 512 + k] * W4[(size_t)l * 512 * 256 + (size_t)k * 256 + n];
    b34c[j] = s;
  }
}

// c1p[l][n] = c1[l]@W34c[l][:,n],  c2p[l][n] = c2[l]@W34c[l][:,n]   (W34T bf16 [l][n][k])
__global__ __launch_bounds__(256) void compose_c_k(
    const float* __restrict__ cb2, const unsigned short* __restrict__ W34T,
    float* __restrict__ c1p, float* __restrict__ c2p)
{
  const int idx = blockIdx.x * 256 + threadIdx.x;
  if (idx >= 5 * 256) return;
  const int l = idx >> 8, n = idx & 255;
  const unsigned short* wr = W34T + ((size_t)l * 256 + n) * 512;
  float a = 0.f, b = 0.f;
  for (int k = 0; k < 512; ++k){
    const float w = bf2f(wr[k]);
    a += cb2[l * 1280 + k] * w;
    b += cb2[l * 1280 + 768 + k] * w;
  }
  c1p[idx] = a;
  c2p[idx] = b;
}

extern "C" void kernel_launch(void* const* d_in, const int* in_sizes, int n_in,
                              void* d_out, int out_size, void* d_ws, size_t ws_size,
                              hipStream_t stream)
{
  const float* obj_in  = (const float*)d_in[0];
  const float* pred_in = (const float*)d_in[1];
  const int*   edges   = (const int*)d_in[2];
  const float* W1 = (const float*)d_in[3];
  const float* b1 = (const float*)d_in[4];
  const float* W2 = (const float*)d_in[5];
  const float* b2 = (const float*)d_in[6];
  const float* W3 = (const float*)d_in[7];
  const float* b3 = (const float*)d_in[8];
  const float* W4 = (const float*)d_in[9];
  const float* b4 = (const float*)d_in[10];
  float* out = (float*)d_out;

  char* p = (char*)d_ws;
  auto alloc = [&](size_t bytes){ char* r = p; p += (bytes + 255) & ~(size_t)255; return r; };

  // weight staging (bf16)
  unsigned short* W1bf  = (unsigned short*)alloc((size_t)5 * 768 * 512 * 2);
  unsigned short* W2pT  = (unsigned short*)alloc((size_t)5 * 256 * 512 * 2);
  unsigned short* W2sT  = (unsigned short*)alloc((size_t)5 * 512 * 512 * 2);
  unsigned short* W2oT  = (unsigned short*)alloc((size_t)5 * 512 * 512 * 2);
  unsigned short* W3bf  = (unsigned short*)alloc((size_t)5 * 512 * 512 * 2);
  unsigned short* W4T   = (unsigned short*)alloc((size_t)5 * 256 * 512 * 2);
  // composed weights
  unsigned short* Wso_rm = (unsigned short*)alloc((size_t)5 * 1536 * 512 * 2); // W1@[W2s;W2o], row-major
  unsigned short* W34T   = (unsigned short*)alloc((size_t)5 * 256 * 512 * 2);  // (W3@W4)^T
  unsigned short* WWT    = (unsigned short*)alloc((size_t)5 * 256 * 1536 * 2); // (Wso@W34)^T
  unsigned short* WpSOT  = (unsigned short*)alloc((size_t)5 * 512 * 256 * 2);  // [Wp_s|Wp_o]^T
  unsigned short* WpPT   = (unsigned short*)alloc((size_t)5 * 256 * 256 * 2);  // Wp_p^T
  float* cb2  = (float*)alloc((size_t)5 * 1280 * 4);
  float* b34c = (float*)alloc((size_t)5 * 256 * 4);
  float* c1p  = (float*)alloc((size_t)5 * 256 * 4);
  float* c2p  = (float*)alloc((size_t)5 * 256 * 4);
  // activations
  unsigned short* objA    = (unsigned short*)alloc((size_t)NOBJ * DD * 2);   // 10.2 MB
  unsigned short* objB    = (unsigned short*)alloc((size_t)NOBJ * DD * 2);   // 10.2 MB
  unsigned short* pred_bf = (unsigned short*)alloc((size_t)NTRI * DD * 2);   // 30.7 MB
  unsigned short* tSO     = (unsigned short*)alloc((size_t)NOBJ * 1536 * 2); // 61.4 MB
  // overlays into tSO (dead after GEMM_A):
  unsigned short* objSO = tSO;                                   // 20.5 MB
  unsigned short* predP = tSO + (size_t)NOBJ * 512;              // 30.7 MB (fallback only)
  // CSR
  int2* eidx  = (int2*)alloc((size_t)NTRI * 8);
  int*  offs  = (int*)alloc((NOBJ + 1) * 4);
  int2* slots = (int2*)alloc((size_t)2 * NTRI * 8);
  int* cnt_s  = (int*)alloc(NOBJ * 4);
  int* cnt_o  = (int*)alloc(NOBJ * 4);
  int* cursor = (int*)alloc(NOBJ * 4);
  int* flag   = (int*)alloc(256);

  // pred double-buffer for the fused-epilogue path, only if workspace allows
  // (in-place fused write would race other n-tile blocks still reading A rows).
  unsigned short* predB = nullptr;
  {
    const size_t used = (size_t)(p - (char*)d_ws);
    if (ws_size >= used + (size_t)NTRI * DD * 2 + 512)
      predB = (unsigned short*)alloc((size_t)NTRI * DD * 2);
  }

  // ---- CSR preamble (edges are layer-invariant) ----
  (void)hipMemsetAsync(cnt_s, 0, NOBJ * 4, stream);
  (void)hipMemsetAsync(cnt_o, 0, NOBJ * 4, stream);
  (void)hipMemsetAsync(flag, 0, 4, stream);
  const int EB = (NTRI + 255) / 256;
  detect_k<<<EB, 256, 0, stream>>>(edges, flag);
  norm_k<<<EB, 256, 0, stream>>>(edges, flag, eidx);
  deg_k<<<EB, 256, 0, stream>>>(eidx, cnt_s, cnt_o);
  scan_k<<<1, 1024, 0, stream>>>(cnt_s, cnt_o, offs);
  (void)hipMemcpyAsync(cursor, offs, NOBJ * 4, hipMemcpyDeviceToDevice, stream);
  fill_k<<<EB, 256, 0, stream>>>(eidx, cursor, slots);

  // ---- inputs -> bf16 ----
  conv_f2b_k<<<(NOBJ * DD / 4 + 255) / 256, 256, 0, stream>>>(obj_in, objA, NOBJ * DD / 4);
  conv_f2b_k<<<(NTRI * DD / 4 + 255) / 256, 256, 0, stream>>>(pred_in, pred_bf, NTRI * DD / 4);

  // ---- weight staging ----
  conv_f2b_k<<<(5 * 768 * 512 / 4 + 255) / 256, 256, 0, stream>>>(W1, W1bf, 5 * 768 * 512 / 4);
  conv_f2b_k<<<(5 * 512 * 512 / 4 + 255) / 256, 256, 0, stream>>>(W3, W3bf, 5 * 512 * 512 / 4);
  conv_wT_k<<<(5 * 256 * 512 + 255) / 256, 256, 0, stream>>>(W2, W2pT, 256, 1280, 512, 512L*1280, 256L*512);
  conv_wT_k<<<(5 * 512 * 512 + 255) / 256, 256, 0, stream>>>(W2, W2sT, 512, 1280, 0,   512L*1280, 512L*512);
  conv_wT_k<<<(5 * 512 * 512 + 255) / 256, 256, 0, stream>>>(W2, W2oT, 512, 1280, 768, 512L*1280, 512L*512);
  conv_wT_k<<<(5 * 256 * 512 + 255) / 256, 256, 0, stream>>>(W4, W4T,  256, 256,  0,   512L*256,  256L*512);
  biascomp_k<<<30, 256, 0, stream>>>(b1, W2, b2, b3, W4, b4, cb2, b34c);

#define NP5 nullptr, nullptr, nullptr, nullptr, nullptr, nullptr, nullptr
  // ---- weight composition GEMMs (grid.z = 5 layers) ----
  // Wso_rm rows [0,768) = W1@W2s (row-major)
  gemm64_k<5><<<dim3(8, 12, 5), 256, 0, stream>>>(W1bf, W2sT, NP5,
      Wso_rm, 768, 512, 512, 0, 768L*512, 512L*512, 1536L*512);
  // Wso_rm rows [768,1536) = W1@W2o
  gemm64_k<5><<<dim3(8, 12, 5), 256, 0, stream>>>(W1bf, W2oT, NP5,
      Wso_rm + (size_t)768*512, 768, 512, 512, 0, 768L*512, 512L*512, 1536L*512);
  // W34T = (W3@W4)^T
  gemm64_k<3><<<dim3(4, 8, 5), 256, 0, stream>>>(W3bf, W4T, NP5,
      W34T, 512, 512, 256, 512, 512L*512, 256L*512, 256L*512);
  // WWT = (Wso @ W34)^T   [1536x512 @ 512x256]
  gemm64_k<3><<<dim3(4, 24, 5), 256, 0, stream>>>(Wso_rm, W34T, NP5,
      WWT, 1536, 512, 256, 1536, 1536L*512, 256L*512, 256L*1536);
  // WpSOT[n<256] = (W1[0:256]@W2p)^T ; [n>=256] = (W1[512:768]@W2p)^T
  gemm64_k<3><<<dim3(4, 4, 5), 256, 0, stream>>>(W1bf, W2pT, NP5,
      WpSOT, 256, 512, 256, 256, 768L*512, 256L*512, 512L*256);
  gemm64_k<3><<<dim3(4, 4, 5), 256, 0, stream>>>(W1bf + (size_t)512*512, W2pT, NP5,
      WpSOT + (size_t)256*256, 256, 512, 256, 256, 768L*512, 256L*512, 512L*256);
  // WpPT = (W1[256:512]@W2p)^T
  gemm64_k<3><<<dim3(4, 4, 5), 256, 0, stream>>>(W1bf + (size_t)256*512, W2pT, NP5,
      WpPT, 256, 512, 256, 256, 768L*512, 256L*512, 256L*256);
  // composed epilogue biases
  compose_c_k<<<5, 256, 0, stream>>>(cb2, W34T, c1p, c2p);

  // ---- layers ----
  unsigned short* objbuf[2]  = { objA, objB };
  unsigned short* predbuf[2] = { pred_bf, predB };
  int cur = 0, pc = 0;
  const int GY_OBJ = (NOBJ + 63) / 64;   // 313
  const int GY_TRI = (NTRI + 63) / 64;   // 938
  for (int l = 0; l < 5; ++l){
    const unsigned short* objc  = objbuf[cur];
    const unsigned short* predc = predbuf[pc];
    // tSO = role-split t-space segment sums
    pool_t_k<<<NOBJ, 256, 0, stream>>>(objc, predc, offs, slots, cnt_s, cnt_o, tSO);
    // new_obj = (tSO@WW + ns*c1p + no*c2p)/max(deg,1) + b34c   (20000x1536x256)
    if (l < 4)
      gemm64_k<2><<<dim3(4, GY_OBJ), 256, 0, stream>>>(tSO, WWT + (size_t)l*256*1536,
          c1p + l*256, c2p + l*256, b34c + l*256, cnt_s, cnt_o, nullptr, nullptr,
          objbuf[cur ^ 1], NOBJ, 1536, DD, 0, 0, 0, 0);
    else
      gemm64_k<6><<<dim3(4, GY_OBJ), 256, 0, stream>>>(tSO, WWT + (size_t)l*256*1536,
          c1p + l*256, c2p + l*256, b34c + l*256, cnt_s, cnt_o, nullptr, nullptr,
          out, NOBJ, 1536, DD, 0, 0, 0, 0);
    // objSO = obj @ [Wp_s|Wp_o]   (20000x256x512) — overlays tSO (dead now)
    gemm64_k<5><<<dim3(8, GY_OBJ), 256, 0, stream>>>(objc, WpSOT + (size_t)l*512*256,
        NP5, objSO, NOBJ, 256, 512, 0, 0, 0, 0);
    if (predB){
      // fused: new_pred = pred@Wp_p + b12p + gather(objSO)   (60000x256x256)
      if (l < 4)
        gemm64_k<7><<<dim3(4, GY_TRI), 256, 0, stream>>>(predc, WpPT + (size_t)l*256*256,
            cb2 + (size_t)l*1280 + 512, nullptr, nullptr, nullptr, nullptr, eidx, objSO,
            predbuf[pc ^ 1], NTRI, 256, DD, 0, 0, 0, 0);
      else
        gemm64_k<8><<<dim3(4, GY_TRI), 256, 0, stream>>>(predc, WpPT + (size_t)l*256*256,
            cb2 + (size_t)l*1280 + 512, nullptr, nullptr, nullptr, nullptr, eidx, objSO,
            out + (size_t)NOBJ * DD, NTRI, 256, DD, 0, 0, 0, 0);
      pc ^= 1;
    } else {
      // fallback: predP then add_k (in-place pred update, no double buffer)
      gemm64_k<0><<<dim3(4, GY_TRI), 256, 0, stream>>>(predc, WpPT + (size_t)l*256*256,
          cb2 + (size_t)l*1280 + 512, nullptr, nullptr, nullptr, nullptr, nullptr, nullptr,
          predP, NTRI, 256, DD, 0, 0, 0, 0);
      if (l < 4)
        add_k<0><<<(NTRI * 64 + 255) / 256, 256, 0, stream>>>(predP, objSO, eidx, pred_bf);
      else
        add_k<1><<<(NTRI * 64 + 255) / 256, 256, 0, stream>>>(predP, objSO, eidx, out + (size_t)NOBJ * DD);
    }
    cur ^= 1;
  }
#undef NP5
}

// Round 4
// 995.040 us; speedup vs baseline: 1.0250x; 1.0250x over previous
//
#include <hip/hip_runtime.h>

// GraphTripleConvNet, fully linear -> aggressive weight composition.
// Round 7: revert r6 dbuf (regressed: barrier still drains vmcnt(0), LDS 2x cut
// residency). Back to 5b single-buffer 2-sync loop. NEW: tile templated
// <MODE,BM,BN>; layer GEMMs use 128x64 (wave-tile 64x32) to cut LDS traffic
// per FLOP ~40% (64x64 tile is LDS-pipe-bound at ~33% MfmaUtil ceiling).
// Preamble GEMMs stay 64x64 (small M needs block count).
//
// Per layer:
//   pool_t : tSO[o] = [ns*obj|SUMs pred|SUMs obj[o']|SUMo obj[s']|SUMo pred|no*obj]
//   GEMM_A : new_obj = (tSO @ (W12so@W34) + ns*c1' + no*c2')/max(deg,1) + b34   (K=1536,N=256)
//   GEMM_C : objSO   = obj @ [Wp_s|Wp_o]                                        (K=256, N=512)
//   GEMM_B : new_pred[e] = pred@Wp_p + b12p + objSO[s_e][0:256] + objSO[o_e][256:512]  (fused)

#define NTRI 60000
#define NOBJ 20000
#define DD 256
#define HH 512

typedef __attribute__((ext_vector_type(8))) short bf16x8;
typedef __attribute__((ext_vector_type(4))) float f32x4;

#define GLDS(gp, lp) __builtin_amdgcn_global_load_lds( \
    (const __attribute__((address_space(1))) void*)(gp), \
    (__attribute__((address_space(3))) void*)(lp), 16, 0, 0)

__device__ __forceinline__ unsigned short f2bf(float f){
  unsigned int x = __builtin_bit_cast(unsigned int, f);
  x += 0x7fffu + ((x >> 16) & 1u);   // RNE
  return (unsigned short)(x >> 16);
}
__device__ __forceinline__ float bf2f(unsigned short u){
  return __builtin_bit_cast(float, (unsigned int)u << 16);
}

// ---------------------------------------------------------------------------
// C(MxN) = A(MxK,bf16) @ Bt(NxK,bf16)^T [+ epilogue].  BMxBN tile, BK=64,
// 4 waves (2x2 wave grid), each wave (BM/32)x(BN/32) frags of 16x16x32 mfma.
// K % 64 == 0, N % BN == 0; M guarded.  grid.z batching via strides (elements).
// Single-buffer 2-sync loop (r6 dbuf regressed).  LDS XOR-swizzled: GLDS dest
// linear, global source kp carries the inverse permutation (both-sides rule).
// MODE 0: bf16 + bias[col].
// MODE 2: bf16, v = (acc + ns*bias + no*bias2)/max(ns+no,1) + bias3.
// MODE 6: fp32, same epilogue as MODE 2.
// MODE 3: bf16 transposed store out[col*ldT+row] (weight composition).
// MODE 5: bf16, no bias.
// MODE 7: bf16, v = acc + bias[col] + gath[s_e][col] + gath[o_e][256+col].
// MODE 8: fp32, same epilogue as MODE 7.
// ---------------------------------------------------------------------------
template<int MODE, int BM, int BN>
__global__ __launch_bounds__(256) void gemm64_k(
    const unsigned short* __restrict__ A,
    const unsigned short* __restrict__ Bt,
    const float* __restrict__ bias,
    const float* __restrict__ bias2,
    const float* __restrict__ bias3,
    const int* __restrict__ cntS,
    const int* __restrict__ cntO,
    const int2* __restrict__ eidx,
    const unsigned short* __restrict__ gath,
    void* __restrict__ out0,
    int M, int K, int N, int ldT,
    long strideA, long strideB, long strideC)
{
  constexpr int MI = BM / 32;            // A-frag count per wave == A GLDS passes
  constexpr int NI = BN / 32;
  __shared__ unsigned short sA[BM * 64];
  __shared__ unsigned short sB[BN * 64];
  const int tid  = threadIdx.x;
  const int lane = tid & 63;
  const int wv   = tid >> 6;
  const int wm   = wv & 1;
  const int wn   = wv >> 1;
  const int quad = lane >> 4;
  const int l15  = lane & 15;

  // bijective XCD-chunked swizzle (m204): consecutive logical blocks (the
  // n-tiles sharing an A-row panel) land on the SAME XCD -> A reread = L2 hit.
  const int nxy = gridDim.x * gridDim.y;
  int bid = blockIdx.y * gridDim.x + blockIdx.x;
  {
    const int q = nxy >> 3, r = nxy & 7;
    const int x = bid & 7, i = bid >> 3;
    bid = (x < r ? x * (q + 1) : r * (q + 1) + (x - r) * q) + i;
  }
  const int m0 = (bid / gridDim.x) * BM;
  const int n0 = (bid % gridDim.x) * BN;
  const size_t zb = blockIdx.z;
  A  += zb * strideA;
  Bt += zb * strideB;

  f32x4 acc[MI][NI] = {};

  const int rr = tid >> 3;                               // staging row 0..31
  const int kp = (((tid & 7) ^ (rr & 7)) << 3);          // pre-swizzled k chunk
  const unsigned short* gA[MI];
  const unsigned short* gB[NI];
#pragma unroll
  for (int i = 0; i < MI; ++i){
    int r = m0 + rr + 32 * i;                            // (r&7)==(rr&7): kp valid
    r = (r < M) ? r : (M - 1);                           // clamped; stores guarded
    gA[i] = A + (size_t)r * K + kp;
  }
#pragma unroll
  for (int i = 0; i < NI; ++i)
    gB[i] = Bt + (size_t)(n0 + rr + 32 * i) * K + kp;

  const int swq = lane & 7;                              // == frag_row & 7
  const int t8  = tid * 8;

  for (int k0 = 0; k0 < K; k0 += 64){
    __syncthreads();
#pragma unroll
    for (int i = 0; i < MI; ++i){ GLDS(gA[i], sA + t8 + 2048 * i); gA[i] += 64; }
#pragma unroll
    for (int i = 0; i < NI; ++i){ GLDS(gB[i], sB + t8 + 2048 * i); gB[i] += 64; }
    __syncthreads();
    bf16x8 af[2][MI], bq[2][NI];
#pragma unroll
    for (int kc = 0; kc < 2; ++kc){
      const int sw = (((kc * 4 + quad) ^ swq) << 3);     // swizzled read offset
#pragma unroll
      for (int mt = 0; mt < MI; ++mt)
        af[kc][mt] = *(const bf16x8*)(sA + (wm*(BM/2) + mt*16 + l15)*64 + sw);
#pragma unroll
      for (int nt = 0; nt < NI; ++nt)
        bq[kc][nt] = *(const bf16x8*)(sB + (wn*(BN/2) + nt*16 + l15)*64 + sw);
    }
#pragma unroll
    for (int kc = 0; kc < 2; ++kc)
#pragma unroll
      for (int mt = 0; mt < MI; ++mt)
#pragma unroll
        for (int nt = 0; nt < NI; ++nt)
          acc[mt][nt] = __builtin_amdgcn_mfma_f32_16x16x32_bf16(af[kc][mt], bq[kc][nt], acc[mt][nt], 0, 0, 0);
  }

  // C/D layout: col = l15, row = quad*4 + reg   [m89-verified]
  if constexpr (MODE == 3){
    unsigned short* outp = (unsigned short*)out0 + zb * strideC;
#pragma unroll
    for (int mt = 0; mt < MI; ++mt){
      const int rb = m0 + wm*(BM/2) + mt*16 + quad*4;
#pragma unroll
      for (int nt = 0; nt < NI; ++nt){
        const int col = n0 + wn*(BN/2) + nt*16 + l15;
        ushort4 r4;
        r4.x = f2bf(acc[mt][nt][0]); r4.y = f2bf(acc[mt][nt][1]);
        r4.z = f2bf(acc[mt][nt][2]); r4.w = f2bf(acc[mt][nt][3]);
        *(ushort4*)(outp + (size_t)col * ldT + rb) = r4;
      }
    }
  } else if constexpr (MODE == 7 || MODE == 8){
#pragma unroll
    for (int mt = 0; mt < MI; ++mt){
      const int rb = m0 + wm*(BM/2) + mt*16 + quad*4;
#pragma unroll
      for (int r = 0; r < 4; ++r){
        const int row = rb + r;
        if (row >= M) continue;
        const int2 ei = eidx[row];
        const unsigned short* srow = gath + (size_t)ei.x * 512;
        const unsigned short* orow = gath + (size_t)ei.y * 512 + 256;
#pragma unroll
        for (int nt = 0; nt < NI; ++nt){
          const int col = n0 + wn*(BN/2) + nt*16 + l15;
          const float v = acc[mt][nt][r] + bias[col] + bf2f(srow[col]) + bf2f(orow[col]);
          if constexpr (MODE == 8) ((float*)out0)[(size_t)row * N + col] = v;
          else ((unsigned short*)out0)[(size_t)row * N + col] = f2bf(v);
        }
      }
    }
  } else {
    char* outp = (char*)out0 + zb * strideC * ((MODE == 6) ? 4 : 2);
#pragma unroll
    for (int mt = 0; mt < MI; ++mt){
      const int rb = m0 + wm*(BM/2) + mt*16 + quad*4;
#pragma unroll
      for (int nt = 0; nt < NI; ++nt){
        const int col = n0 + wn*(BN/2) + nt*16 + l15;
#pragma unroll
        for (int r = 0; r < 4; ++r){
          const int row = rb + r;
          if (row >= M) continue;
          float v = acc[mt][nt][r];
          if constexpr (MODE == 0) v += bias[col];
          if constexpr (MODE == 2 || MODE == 6){
            const float ns = (float)cntS[row], no = (float)cntO[row];
            v = (v + ns * bias[col] + no * bias2[col]) / fmaxf(ns + no, 1.f) + bias3[col];
          }
          if constexpr (MODE == 6) ((float*)outp)[(size_t)row * N + col] = v;
          else                     ((unsigned short*)outp)[(size_t)row * N + col] = f2bf(v);
        }
      }
    }
  }
}

// --- edges dtype autodetect ---
__global__ __launch_bounds__(256) void detect_k(const int* __restrict__ e, int* __restrict__ flag)
{
  const int i = blockIdx.x * 256 + threadIdx.x;
  if (i >= NTRI) return;
  if (e[2*i + 1] != 0) atomicOr(flag, 1);   // any nonzero odd word => int32 layout
}

__global__ __launch_bounds__(256) void norm_k(const int* __restrict__ e, const int* __restrict__ flag,
                                              int2* __restrict__ eidx)
{
  const int i = blockIdx.x * 256 + threadIdx.x;
  if (i >= NTRI) return;
  int s, o;
  if (*flag){ s = e[2*i]; o = e[2*i + 1]; }
  else      { s = e[4*i]; o = e[4*i + 2]; }
  s = min(max(s, 0), NOBJ - 1);
  o = min(max(o, 0), NOBJ - 1);
  eidx[i] = make_int2(s, o);
}

__global__ __launch_bounds__(256) void deg_k(const int2* __restrict__ eidx,
                                             int* __restrict__ cnt_s, int* __restrict__ cnt_o)
{
  const int i = blockIdx.x * 256 + threadIdx.x;
  if (i >= NTRI) return;
  atomicAdd(&cnt_s[eidx[i].x], 1);
  atomicAdd(&cnt_o[eidx[i].y], 1);
}

__global__ __launch_bounds__(1024) void scan_k(const int* __restrict__ cnt_s,
                                               const int* __restrict__ cnt_o,
                                               int* __restrict__ offs)
{
  __shared__ int sd[1024];
  __shared__ int carry;
  if (threadIdx.x == 0) carry = 0;
  __syncthreads();
  const int nIter = (NOBJ + 1023) / 1024;
  for (int it = 0; it < nIter; ++it){
    const int i = it * 1024 + (int)threadIdx.x;
    const int v = (i < NOBJ) ? (cnt_s[i] + cnt_o[i]) : 0;
    sd[threadIdx.x] = v;
    __syncthreads();
    for (int off = 1; off < 1024; off <<= 1){
      const int t = ((int)threadIdx.x >= off) ? sd[threadIdx.x - off] : 0;
      __syncthreads();
      sd[threadIdx.x] += t;
      __syncthreads();
    }
    if (i < NOBJ) offs[i] = carry + sd[threadIdx.x] - v;
    __syncthreads();
    if (threadIdx.x == 0){
      carry += sd[1023];
      if (it == nIter - 1) offs[NOBJ] = carry;
    }
    __syncthreads();
  }
}

// slot payload: (2*e+role, other_object_index)
__global__ __launch_bounds__(256) void fill_k(const int2* __restrict__ eidx,
                                              int* __restrict__ cursor, int2* __restrict__ slots)
{
  const int i = blockIdx.x * 256 + threadIdx.x;
  if (i >= NTRI) return;
  const int2 e = eidx[i];
  slots[atomicAdd(&cursor[e.x], 1)] = make_int2(2*i,     e.y);   // subject role
  slots[atomicAdd(&cursor[e.y], 1)] = make_int2(2*i + 1, e.x);   // object role
}

// tSO[o][1536] = [ns*obj[o] | SUMs pred | SUMs obj[oidx] | SUMo obj[sidx] | SUMo pred | no*obj[o]]
// v2: ushort4 loads (8B/lane), 4 slot-groups in parallel, LDS tree-combine.
__global__ __launch_bounds__(256) void pool_t_k(
    const unsigned short* __restrict__ obj, const unsigned short* __restrict__ pred,
    const int* __restrict__ offs, const int2* __restrict__ slots,
    const int* __restrict__ cnt_s, const int* __restrict__ cnt_o,
    unsigned short* __restrict__ tSO)
{
  __shared__ __align__(16) float red[4][4][256];   // [group][sum][ch] 16KB
  const int o    = blockIdx.x;
  const int tid  = (int)threadIdx.x;
  const int g    = tid >> 6;
  const int lane = tid & 63;
  const int c4   = lane << 2;
  const int b0 = offs[o], b1 = offs[o + 1];
  float sp0=0.f, sp1=0.f, sp2=0.f, sp3=0.f;
  float so0=0.f, so1=0.f, so2=0.f, so3=0.f;
  float oo0=0.f, oo1=0.f, oo2=0.f, oo3=0.f;
  float op0=0.f, op1=0.f, op2=0.f, op3=0.f;
  for (int j = b0 + g; j < b1; j += 4){
    const int2 sl = slots[j];
    const ushort4 pv = *(const ushort4*)(pred + (size_t)(sl.x >> 1) * DD + c4);
    const ushort4 ov = *(const ushort4*)(obj  + (size_t)sl.y * DD + c4);
    const float p0 = bf2f(pv.x), p1 = bf2f(pv.y), p2 = bf2f(pv.z), p3 = bf2f(pv.w);
    const float q0 = bf2f(ov.x), q1 = bf2f(ov.y), q2 = bf2f(ov.z), q3 = bf2f(ov.w);
    if (sl.x & 1){ op0+=p0; op1+=p1; op2+=p2; op3+=p3; oo0+=q0; oo1+=q1; oo2+=q2; oo3+=q3; }
    else         { sp0+=p0; sp1+=p1; sp2+=p2; sp3+=p3; so0+=q0; so1+=q1; so2+=q2; so3+=q3; }
  }
  red[g][0][c4+0]=sp0; red[g][0][c4+1]=sp1; red[g][0][c4+2]=sp2; red[g][0][c4+3]=sp3;
  red[g][1][c4+0]=so0; red[g][1][c4+1]=so1; red[g][1][c4+2]=so2; red[g][1][c4+3]=so3;
  red[g][2][c4+0]=oo0; red[g][2][c4+1]=oo1; red[g][2][c4+2]=oo2; red[g][2][c4+3]=oo3;
  red[g][3][c4+0]=op0; red[g][3][c4+1]=op1; red[g][3][c4+2]=op2; red[g][3][c4+3]=op3;
  __syncthreads();
  unsigned short* dst = tSO + (size_t)o * 1536;
#define TOTW(s, off) { \
    const float4 t0 = *(const float4*)&red[0][s][c4]; \
    const float4 t1 = *(const float4*)&red[1][s][c4]; \
    const float4 t2 = *(const float4*)&red[2][s][c4]; \
    const float4 t3 = *(const float4*)&red[3][s][c4]; \
    ushort4 w; \
    w.x = f2bf(t0.x + t1.x + t2.x + t3.x); \
    w.y = f2bf(t0.y + t1.y + t2.y + t3.y); \
    w.z = f2bf(t0.z + t1.z + t2.z + t3.z); \
    w.w = f2bf(t0.w + t1.w + t2.w + t3.w); \
    *(ushort4*)(dst + (off) + c4) = w; }
  if (g == 0){
    const ushort4 ob = *(const ushort4*)(obj + (size_t)o * DD + c4);
    const float ns = (float)cnt_s[o];
    ushort4 w;
    w.x = f2bf(ns * bf2f(ob.x)); w.y = f2bf(ns * bf2f(ob.y));
    w.z = f2bf(ns * bf2f(ob.z)); w.w = f2bf(ns * bf2f(ob.w));
    *(ushort4*)(dst + c4) = w;
    TOTW(0, 256);
  } else if (g == 1){
    TOTW(1, 512);
  } else if (g == 2){
    TOTW(2, 768);
    const ushort4 ob = *(const ushort4*)(obj + (size_t)o * DD + c4);
    const float no = (float)cnt_o[o];
    ushort4 w;
    w.x = f2bf(no * bf2f(ob.x)); w.y = f2bf(no * bf2f(ob.y));
    w.z = f2bf(no * bf2f(ob.z)); w.w = f2bf(no * bf2f(ob.w));
    *(ushort4*)(dst + 1280 + c4) = w;
  } else {
    TOTW(3, 1024);
  }
#undef TOTW
}

// fallback path only: new_pred[e][c] = predP[e][c] + objSO[s_e][c] + objSO[o_e][256+c]
template<int OUT>
__global__ __launch_bounds__(256) void add_k(
    const unsigned short* __restrict__ predP, const unsigned short* __restrict__ objSO,
    const int2* __restrict__ eidx, void* __restrict__ outp)
{
  const int i = blockIdx.x * 256 + threadIdx.x;
  if (i >= NTRI * 64) return;
  const int e  = i >> 6;
  const int c4 = (i & 63) << 2;
  const int2 ei = eidx[e];
  const ushort4 a = *(const ushort4*)(predP + (size_t)e * DD + c4);
  const ushort4 s = *(const ushort4*)(objSO + (size_t)ei.x * 512 + c4);
  const ushort4 o = *(const ushort4*)(objSO + (size_t)ei.y * 512 + 256 + c4);
  float v0 = bf2f(a.x) + bf2f(s.x) + bf2f(o.x);
  float v1 = bf2f(a.y) + bf2f(s.y) + bf2f(o.y);
  float v2 = bf2f(a.z) + bf2f(s.z) + bf2f(o.z);
  float v3 = bf2f(a.w) + bf2f(s.w) + bf2f(o.w);
  if constexpr (OUT){
    float4 r = make_float4(v0, v1, v2, v3);
    *(float4*)((float*)outp + (size_t)e * DD + c4) = r;
  } else {
    ushort4 r;
    r.x = f2bf(v0); r.y = f2bf(v1); r.z = f2bf(v2); r.w = f2bf(v3);
    *(ushort4*)((unsigned short*)outp + (size_t)e * DD + c4) = r;
  }
}

// fp32 -> bf16 flat (vector x4)
__global__ __launch_bounds__(256) void conv_f2b_k(const float* __restrict__ x,
                                                  unsigned short* __restrict__ y, int n4)
{
  const int i = blockIdx.x * 256 + threadIdx.x;
  if (i >= n4) return;
  const float4 v = ((const float4*)x)[i];
  ushort4 r;
  r.x = f2bf(v.x); r.y = f2bf(v.y); r.z = f2bf(v.z); r.w = f2bf(v.w);
  ((ushort4*)y)[i] = r;
}

// batched (L=5) transpose-convert: Wt[l][n][k] = bf16(W[l][k][colOff+n]), K=512
__global__ __launch_bounds__(256) void conv_wT_k(
    const float* __restrict__ W, unsigned short* __restrict__ Wt,
    int N, int ldW, int colOff, long wLS, long oLS)
{
  const int idx = blockIdx.x * 256 + threadIdx.x;
  const int per = N * 512;
  if (idx >= 5 * per) return;
  const int l = idx / per;
  const int r = idx - l * per;
  const int n = r >> 9;
  const int k = r & 511;
  Wt[l * oLS + (size_t)n * 512 + k] = f2bf(W[l * wLS + (size_t)k * ldW + colOff + n]);
}

// cb2[l][0..1280) = b1[l]@W2[l] + b2[l];  b34c[l][0..256) = b3[l]@W4[l] + b4[l]
__global__ __launch_bounds__(256) void biascomp_k(
    const float* __restrict__ b1, const float* __restrict__ W2, const float* __restrict__ b2,
    const float* __restrict__ b3, const float* __restrict__ W4, const float* __restrict__ b4,
    float* __restrict__ cb2, float* __restrict__ b34c)
{
  const int idx = blockIdx.x * 256 + threadIdx.x;
  if (idx < 5 * 1280){
    const int l = idx / 1280, n = idx - l * 1280;
    float s = b2[l * 1280 + n];
    for (int k = 0; k < 512; ++k)
      s += b1[l * 512 + k] * W2[(size_t)l * 512 * 1280 + (size_t)k * 1280 + n];
    cb2[idx] = s;
  } else if (idx < 5 * 1280 + 5 * 256){
    const int j = idx - 6400;
    const int l = j / 256, n = j - l * 256;
    float s = b4[l * 256 + n];
    for (int k = 0; k < 512; ++k)
      s += b3[l * 512 + k] * W4[(size_t)l * 512 * 256 + (size_t)k * 256 + n];
    b34c[j] = s;
  }
}

// c1p[l][n] = c1[l]@W34c[l][:,n],  c2p[l][n] = c2[l]@W34c[l][:,n]   (W34T bf16 [l][n][k])
__global__ __launch_bounds__(256) void compose_c_k(
    const float* __restrict__ cb2, const unsigned short* __restrict__ W34T,
    float* __restrict__ c1p, float* __restrict__ c2p)
{
  const int idx = blockIdx.x * 256 + threadIdx.x;
  if (idx >= 5 * 256) return;
  const int l = idx >> 8, n = idx & 255;
  const unsigned short* wr = W34T + ((size_t)l * 256 + n) * 512;
  float a = 0.f, b = 0.f;
  for (int k = 0; k < 512; ++k){
    const float w = bf2f(wr[k]);
    a += cb2[l * 1280 + k] * w;
    b += cb2[l * 1280 + 768 + k] * w;
  }
  c1p[idx] = a;
  c2p[idx] = b;
}

extern "C" void kernel_launch(void* const* d_in, const int* in_sizes, int n_in,
                              void* d_out, int out_size, void* d_ws, size_t ws_size,
                              hipStream_t stream)
{
  const float* obj_in  = (const float*)d_in[0];
  const float* pred_in = (const float*)d_in[1];
  const int*   edges   = (const int*)d_in[2];
  const float* W1 = (const float*)d_in[3];
  const float* b1 = (const float*)d_in[4];
  const float* W2 = (const float*)d_in[5];
  const float* b2 = (const float*)d_in[6];
  const float* W3 = (const float*)d_in[7];
  const float* b3 = (const float*)d_in[8];
  const float* W4 = (const float*)d_in[9];
  const float* b4 = (const float*)d_in[10];
  float* out = (float*)d_out;

  char* p = (char*)d_ws;
  auto alloc = [&](size_t bytes){ char* r = p; p += (bytes + 255) & ~(size_t)255; return r; };

  // weight staging (bf16)
  unsigned short* W1bf  = (unsigned short*)alloc((size_t)5 * 768 * 512 * 2);
  unsigned short* W2pT  = (unsigned short*)alloc((size_t)5 * 256 * 512 * 2);
  unsigned short* W2sT  = (unsigned short*)alloc((size_t)5 * 512 * 512 * 2);
  unsigned short* W2oT  = (unsigned short*)alloc((size_t)5 * 512 * 512 * 2);
  unsigned short* W3bf  = (unsigned short*)alloc((size_t)5 * 512 * 512 * 2);
  unsigned short* W4T   = (unsigned short*)alloc((size_t)5 * 256 * 512 * 2);
  // composed weights
  unsigned short* Wso_rm = (unsigned short*)alloc((size_t)5 * 1536 * 512 * 2); // W1@[W2s;W2o], row-major
  unsigned short* W34T   = (unsigned short*)alloc((size_t)5 * 256 * 512 * 2);  // (W3@W4)^T
  unsigned short* WWT    = (unsigned short*)alloc((size_t)5 * 256 * 1536 * 2); // (Wso@W34)^T
  unsigned short* WpSOT  = (unsigned short*)alloc((size_t)5 * 512 * 256 * 2);  // [Wp_s|Wp_o]^T
  unsigned short* WpPT   = (unsigned short*)alloc((size_t)5 * 256 * 256 * 2);  // Wp_p^T
  float* cb2  = (float*)alloc((size_t)5 * 1280 * 4);
  float* b34c = (float*)alloc((size_t)5 * 256 * 4);
  float* c1p  = (float*)alloc((size_t)5 * 256 * 4);
  float* c2p  = (float*)alloc((size_t)5 * 256 * 4);
  // activations
  unsigned short* objA    = (unsigned short*)alloc((size_t)NOBJ * DD * 2);   // 10.2 MB
  unsigned short* objB    = (unsigned short*)alloc((size_t)NOBJ * DD * 2);   // 10.2 MB
  unsigned short* pred_bf = (unsigned short*)alloc((size_t)NTRI * DD * 2);   // 30.7 MB
  unsigned short* tSO     = (unsigned short*)alloc((size_t)NOBJ * 1536 * 2); // 61.4 MB
  // overlays into tSO (dead after GEMM_A):
  unsigned short* objSO = tSO;                                   // 20.5 MB
  unsigned short* predP = tSO + (size_t)NOBJ * 512;              // 30.7 MB (fallback only)
  // CSR
  int2* eidx  = (int2*)alloc((size_t)NTRI * 8);
  int*  offs  = (int*)alloc((NOBJ + 1) * 4);
  int2* slots = (int2*)alloc((size_t)2 * NTRI * 8);
  int* cnt_s  = (int*)alloc(NOBJ * 4);
  int* cnt_o  = (int*)alloc(NOBJ * 4);
  int* cursor = (int*)alloc(NOBJ * 4);
  int* flag   = (int*)alloc(256);

  // pred double-buffer for the fused-epilogue path, only if workspace allows
  // (in-place fused write would race other n-tile blocks still reading A rows).
  unsigned short* predB = nullptr;
  {
    const size_t used = (size_t)(p - (char*)d_ws);
    if (ws_size >= used + (size_t)NTRI * DD * 2 + 512)
      predB = (unsigned short*)alloc((size_t)NTRI * DD * 2);
  }

  // ---- CSR preamble (edges are layer-invariant) ----
  (void)hipMemsetAsync(cnt_s, 0, NOBJ * 4, stream);
  (void)hipMemsetAsync(cnt_o, 0, NOBJ * 4, stream);
  (void)hipMemsetAsync(flag, 0, 4, stream);
  const int EB = (NTRI + 255) / 256;
  detect_k<<<EB, 256, 0, stream>>>(edges, flag);
  norm_k<<<EB, 256, 0, stream>>>(edges, flag, eidx);
  deg_k<<<EB, 256, 0, stream>>>(eidx, cnt_s, cnt_o);
  scan_k<<<1, 1024, 0, stream>>>(cnt_s, cnt_o, offs);
  (void)hipMemcpyAsync(cursor, offs, NOBJ * 4, hipMemcpyDeviceToDevice, stream);
  fill_k<<<EB, 256, 0, stream>>>(eidx, cursor, slots);

  // ---- inputs -> bf16 ----
  conv_f2b_k<<<(NOBJ * DD / 4 + 255) / 256, 256, 0, stream>>>(obj_in, objA, NOBJ * DD / 4);
  conv_f2b_k<<<(NTRI * DD / 4 + 255) / 256, 256, 0, stream>>>(pred_in, pred_bf, NTRI * DD / 4);

  // ---- weight staging ----
  conv_f2b_k<<<(5 * 768 * 512 / 4 + 255) / 256, 256, 0, stream>>>(W1, W1bf, 5 * 768 * 512 / 4);
  conv_f2b_k<<<(5 * 512 * 512 / 4 + 255) / 256, 256, 0, stream>>>(W3, W3bf, 5 * 512 * 512 / 4);
  conv_wT_k<<<(5 * 256 * 512 + 255) / 256, 256, 0, stream>>>(W2, W2pT, 256, 1280, 512, 512L*1280, 256L*512);
  conv_wT_k<<<(5 * 512 * 512 + 255) / 256, 256, 0, stream>>>(W2, W2sT, 512, 1280, 0,   512L*1280, 512L*512);
  conv_wT_k<<<(5 * 512 * 512 + 255) / 256, 256, 0, stream>>>(W2, W2oT, 512, 1280, 768, 512L*1280, 512L*512);
  conv_wT_k<<<(5 * 256 * 512 + 255) / 256, 256, 0, stream>>>(W4, W4T,  256, 256,  0,   512L*256,  256L*512);
  biascomp_k<<<30, 256, 0, stream>>>(b1, W2, b2, b3, W4, b4, cb2, b34c);

#define NP5 nullptr, nullptr, nullptr, nullptr, nullptr, nullptr, nullptr
  // ---- weight composition GEMMs (grid.z = 5 layers), 64x64 tiles ----
  // Wso_rm rows [0,768) = W1@W2s (row-major)
  gemm64_k<5,64,64><<<dim3(8, 12, 5), 256, 0, stream>>>(W1bf, W2sT, NP5,
      Wso_rm, 768, 512, 512, 0, 768L*512, 512L*512, 1536L*512);
  // Wso_rm rows [768,1536) = W1@W2o
  gemm64_k<5,64,64><<<dim3(8, 12, 5), 256, 0, stream>>>(W1bf, W2oT, NP5,
      Wso_rm + (size_t)768*512, 768, 512, 512, 0, 768L*512, 512L*512, 1536L*512);
  // W34T = (W3@W4)^T
  gemm64_k<3,64,64><<<dim3(4, 8, 5), 256, 0, stream>>>(W3bf, W4T, NP5,
      W34T, 512, 512, 256, 512, 512L*512, 256L*512, 256L*512);
  // WWT = (Wso @ W34)^T   [1536x512 @ 512x256]
  gemm64_k<3,64,64><<<dim3(4, 24, 5), 256, 0, stream>>>(Wso_rm, W34T, NP5,
      WWT, 1536, 512, 256, 1536, 1536L*512, 256L*512, 256L*1536);
  // WpSOT[n<256] = (W1[0:256]@W2p)^T ; [n>=256] = (W1[512:768]@W2p)^T
  gemm64_k<3,64,64><<<dim3(4, 4, 5), 256, 0, stream>>>(W1bf, W2pT, NP5,
      WpSOT, 256, 512, 256, 256, 768L*512, 256L*512, 512L*256);
  gemm64_k<3,64,64><<<dim3(4, 4, 5), 256, 0, stream>>>(W1bf + (size_t)512*512, W2pT, NP5,
      WpSOT + (size_t)256*256, 256, 512, 256, 256, 768L*512, 256L*512, 512L*256);
  // WpPT = (W1[256:512]@W2p)^T
  gemm64_k<3,64,64><<<dim3(4, 4, 5), 256, 0, stream>>>(W1bf + (size_t)256*512, W2pT, NP5,
      WpPT, 256, 512, 256, 256, 768L*512, 256L*512, 256L*256);
  // composed epilogue biases
  compose_c_k<<<5, 256, 0, stream>>>(cb2, W34T, c1p, c2p);

  // ---- layers (128x64 tiles) ----
  unsigned short* objbuf[2]  = { objA, objB };
  unsigned short* predbuf[2] = { pred_bf, predB };
  int cur = 0, pc = 0;
  const int GY_OBJ = (NOBJ + 127) / 128;   // 157
  const int GY_TRI = (NTRI + 127) / 128;   // 469
  for (int l = 0; l < 5; ++l){
    const unsigned short* objc  = objbuf[cur];
    const unsigned short* predc = predbuf[pc];
    // tSO = role-split t-space segment sums
    pool_t_k<<<NOBJ, 256, 0, stream>>>(objc, predc, offs, slots, cnt_s, cnt_o, tSO);
    // new_obj = (tSO@WW + ns*c1p + no*c2p)/max(deg,1) + b34c   (20000x1536x256)
    if (l < 4)
      gemm64_k<2,128,64><<<dim3(4, GY_OBJ), 256, 0, stream>>>(tSO, WWT + (size_t)l*256*1536,
          c1p + l*256, c2p + l*256, b34c + l*256, cnt_s, cnt_o, nullptr, nullptr,
          objbuf[cur ^ 1], NOBJ, 1536, DD, 0, 0, 0, 0);
    else
      gemm64_k<6,128,64><<<dim3(4, GY_OBJ), 256, 0, stream>>>(tSO, WWT + (size_t)l*256*1536,
          c1p + l*256, c2p + l*256, b34c + l*256, cnt_s, cnt_o, nullptr, nullptr,
          out, NOBJ, 1536, DD, 0, 0, 0, 0);
    // objSO = obj @ [Wp_s|Wp_o]   (20000x256x512) — overlays tSO (dead now)
    gemm64_k<5,128,64><<<dim3(8, GY_OBJ), 256, 0, stream>>>(objc, WpSOT + (size_t)l*512*256,
        NP5, objSO, NOBJ, 256, 512, 0, 0, 0, 0);
    if (predB){
      // fused: new_pred = pred@Wp_p + b12p + gather(objSO)   (60000x256x256)
      if (l < 4)
        gemm64_k<7,128,64><<<dim3(4, GY_TRI), 256, 0, stream>>>(predc, WpPT + (size_t)l*256*256,
            cb2 + (size_t)l*1280 + 512, nullptr, nullptr, nullptr, nullptr, eidx, objSO,
            predbuf[pc ^ 1], NTRI, 256, DD, 0, 0, 0, 0);
      else
        gemm64_k<8,128,64><<<dim3(4, GY_TRI), 256, 0, stream>>>(predc, WpPT + (size_t)l*256*256,
            cb2 + (size_t)l*1280 + 512, nullptr, nullptr, nullptr, nullptr, eidx, objSO,
            out + (size_t)NOBJ * DD, NTRI, 256, DD, 0, 0, 0, 0);
      pc ^= 1;
    } else {
      // fallback: predP then add_k (in-place pred update, no double buffer)
      gemm64_k<0,128,64><<<dim3(4, GY_TRI), 256, 0, stream>>>(predc, WpPT + (size_t)l*256*256,
          cb2 + (size_t)l*1280 + 512, nullptr, nullptr, nullptr, nullptr, nullptr, nullptr,
          predP, NTRI, 256, DD, 0, 0, 0, 0);
      if (l < 4)
        add_k<0><<<(NTRI * 64 + 255) / 256, 256, 0, stream>>>(predP, objSO, eidx, pred_bf);
      else
        add_k<1><<<(NTRI * 64 + 255) / 256, 256, 0, stream>>>(predP, objSO, eidx, out + (size_t)NOBJ * DD);
    }
    cur ^= 1;
  }
#undef NP5
}

// Round 5
// 950.369 us; speedup vs baseline: 1.0732x; 1.0470x over previous
//
#include <hip/hip_runtime.h>

// GraphTripleConvNet, fully linear -> aggressive weight composition.
// Round 8: cross-kernel overlap. R4 showed GEMM_A at MfmaUtil 12%/Occ 23%:
// latency-bound with only 2.4 blocks/CU. Fix: merge data-independent work
// into single launches so stalled GEMM waves are covered by other work:
//   L1 = pool_t (20000 gather blocks) || GEMM_C (1256 MFMA blocks)
//   L2 = GEMM_A (628 blocks)          || GEMM_B (1876 blocks)
// Requires objSO un-aliased from tSO -> overlaid onto dead preamble staging
// buffers (W1bf..Wso_rm, 22.3MB >= 20.5MB). Layer = 2 launches (was 4).
// GEMM core unchanged from R4 (single-buffer 2-sync, XOR-swizzled LDS).
//
// Per layer:
//   pool_t : tSO[o] = [ns*obj|SUMs pred|SUMs obj[o']|SUMo obj[s']|SUMo pred|no*obj]
//   GEMM_A : new_obj = (tSO @ (W12so@W34) + ns*c1' + no*c2')/max(deg,1) + b34   (K=1536,N=256)
//   GEMM_C : objSO   = obj @ [Wp_s|Wp_o]                                        (K=256, N=512)
//   GEMM_B : new_pred[e] = pred@Wp_p + b12p + objSO[s_e][0:256] + objSO[o_e][256:512]

#define NTRI 60000
#define NOBJ 20000
#define DD 256
#define HH 512

typedef __attribute__((ext_vector_type(8))) short bf16x8;
typedef __attribute__((ext_vector_type(4))) float f32x4;

#define GLDS(gp, lp) __builtin_amdgcn_global_load_lds( \
    (const __attribute__((address_space(1))) void*)(gp), \
    (__attribute__((address_space(3))) void*)(lp), 16, 0, 0)

__device__ __forceinline__ unsigned short f2bf(float f){
  unsigned int x = __builtin_bit_cast(unsigned int, f);
  x += 0x7fffu + ((x >> 16) & 1u);   // RNE
  return (unsigned short)(x >> 16);
}
__device__ __forceinline__ float bf2f(unsigned short u){
  return __builtin_bit_cast(float, (unsigned int)u << 16);
}

// bijective XCD-chunked swizzle (m204): consecutive logical ids (panel-sharing
// n-tiles) land on the SAME XCD chunk -> operand reread = L2 hit.
__device__ __forceinline__ int xcd_chunk(int b, int n){
  const int q = n >> 3, r = n & 7;
  const int x = b & 7, i = b >> 3;
  return (x < r ? x * (q + 1) : r * (q + 1) + (x - r) * q) + i;
}

// ---------------------------------------------------------------------------
// GEMM core: C(MxN) = A(MxK,bf16) @ Bt(NxK,bf16)^T [+ epilogue]. BMxBN tile,
// BK=64, 4 waves (2x2), each wave (BM/32)x(BN/32) frags of 16x16x32 mfma.
// K%64==0, N%BN==0; M guarded. Single-buffer 2-sync loop. LDS XOR-swizzled:
// GLDS dest linear, global source kp carries inverse permutation.
// MODE 0: bf16 + bias[col].
// MODE 2: bf16, v = (acc + ns*bias + no*bias2)/max(ns+no,1) + bias3.
// MODE 6: fp32, same epilogue as MODE 2.
// MODE 3: bf16 transposed store out[col*ldT+row].
// MODE 5: bf16, no bias.
// MODE 7: bf16, v = acc + bias[col] + gath[s_e][col] + gath[o_e][256+col].
// MODE 8: fp32, same epilogue as MODE 7.
// ---------------------------------------------------------------------------
template<int MODE, int BM, int BN>
__device__ __forceinline__ void gemm_core(
    unsigned short* sA, unsigned short* sB,
    const unsigned short* __restrict__ A,
    const unsigned short* __restrict__ Bt,
    const float* __restrict__ bias,
    const float* __restrict__ bias2,
    const float* __restrict__ bias3,
    const int* __restrict__ cntS,
    const int* __restrict__ cntO,
    const int2* __restrict__ eidx,
    const unsigned short* __restrict__ gath,
    void* __restrict__ out0,
    int m0, int n0, int M, int K, int N, int ldT)
{
  constexpr int MI = BM / 32;
  constexpr int NI = BN / 32;
  const int tid  = threadIdx.x;
  const int lane = tid & 63;
  const int wv   = tid >> 6;
  const int wm   = wv & 1;
  const int wn   = wv >> 1;
  const int quad = lane >> 4;
  const int l15  = lane & 15;

  f32x4 acc[MI][NI] = {};

  const int rr = tid >> 3;                               // staging row 0..31
  const int kp = (((tid & 7) ^ (rr & 7)) << 3);          // pre-swizzled k chunk
  const unsigned short* gA[MI];
  const unsigned short* gB[NI];
#pragma unroll
  for (int i = 0; i < MI; ++i){
    int r = m0 + rr + 32 * i;                            // (r&7)==(rr&7): kp valid
    r = (r < M) ? r : (M - 1);                           // clamped; stores guarded
    gA[i] = A + (size_t)r * K + kp;
  }
#pragma unroll
  for (int i = 0; i < NI; ++i)
    gB[i] = Bt + (size_t)(n0 + rr + 32 * i) * K + kp;

  const int swq = lane & 7;                              // == frag_row & 7
  const int t8  = tid * 8;

  for (int k0 = 0; k0 < K; k0 += 64){
    __syncthreads();
#pragma unroll
    for (int i = 0; i < MI; ++i){ GLDS(gA[i], sA + t8 + 2048 * i); gA[i] += 64; }
#pragma unroll
    for (int i = 0; i < NI; ++i){ GLDS(gB[i], sB + t8 + 2048 * i); gB[i] += 64; }
    __syncthreads();
    bf16x8 af[2][MI], bq[2][NI];
#pragma unroll
    for (int kc = 0; kc < 2; ++kc){
      const int sw = (((kc * 4 + quad) ^ swq) << 3);     // swizzled read offset
#pragma unroll
      for (int mt = 0; mt < MI; ++mt)
        af[kc][mt] = *(const bf16x8*)(sA + (wm*(BM/2) + mt*16 + l15)*64 + sw);
#pragma unroll
      for (int nt = 0; nt < NI; ++nt)
        bq[kc][nt] = *(const bf16x8*)(sB + (wn*(BN/2) + nt*16 + l15)*64 + sw);
    }
#pragma unroll
    for (int kc = 0; kc < 2; ++kc)
#pragma unroll
      for (int mt = 0; mt < MI; ++mt)
#pragma unroll
        for (int nt = 0; nt < NI; ++nt)
          acc[mt][nt] = __builtin_amdgcn_mfma_f32_16x16x32_bf16(af[kc][mt], bq[kc][nt], acc[mt][nt], 0, 0, 0);
  }

  // C/D layout: col = l15, row = quad*4 + reg   [m89-verified]
  if constexpr (MODE == 3){
    unsigned short* outp = (unsigned short*)out0;
#pragma unroll
    for (int mt = 0; mt < MI; ++mt){
      const int rb = m0 + wm*(BM/2) + mt*16 + quad*4;
#pragma unroll
      for (int nt = 0; nt < NI; ++nt){
        const int col = n0 + wn*(BN/2) + nt*16 + l15;
        ushort4 r4;
        r4.x = f2bf(acc[mt][nt][0]); r4.y = f2bf(acc[mt][nt][1]);
        r4.z = f2bf(acc[mt][nt][2]); r4.w = f2bf(acc[mt][nt][3]);
        *(ushort4*)(outp + (size_t)col * ldT + rb) = r4;
      }
    }
  } else if constexpr (MODE == 7 || MODE == 8){
#pragma unroll
    for (int mt = 0; mt < MI; ++mt){
      const int rb = m0 + wm*(BM/2) + mt*16 + quad*4;
#pragma unroll
      for (int r = 0; r < 4; ++r){
        const int row = rb + r;
        if (row >= M) continue;
        const int2 ei = eidx[row];
        const unsigned short* srow = gath + (size_t)ei.x * 512;
        const unsigned short* orow = gath + (size_t)ei.y * 512 + 256;
#pragma unroll
        for (int nt = 0; nt < NI; ++nt){
          const int col = n0 + wn*(BN/2) + nt*16 + l15;
          const float v = acc[mt][nt][r] + bias[col] + bf2f(srow[col]) + bf2f(orow[col]);
          if constexpr (MODE == 8) ((float*)out0)[(size_t)row * N + col] = v;
          else ((unsigned short*)out0)[(size_t)row * N + col] = f2bf(v);
        }
      }
    }
  } else {
#pragma unroll
    for (int mt = 0; mt < MI; ++mt){
      const int rb = m0 + wm*(BM/2) + mt*16 + quad*4;
#pragma unroll
      for (int nt = 0; nt < NI; ++nt){
        const int col = n0 + wn*(BN/2) + nt*16 + l15;
#pragma unroll
        for (int r = 0; r < 4; ++r){
          const int row = rb + r;
          if (row >= M) continue;
          float v = acc[mt][nt][r];
          if constexpr (MODE == 0) v += bias[col];
          if constexpr (MODE == 2 || MODE == 6){
            const float ns = (float)cntS[row], no = (float)cntO[row];
            v = (v + ns * bias[col] + no * bias2[col]) / fmaxf(ns + no, 1.f) + bias3[col];
          }
          if constexpr (MODE == 6) ((float*)out0)[(size_t)row * N + col] = v;
          else                     ((unsigned short*)out0)[(size_t)row * N + col] = f2bf(v);
        }
      }
    }
  }
}

// standalone wrapper (preamble weight GEMMs + fallback path), grid.z batching.
template<int MODE, int BM, int BN>
__global__ __launch_bounds__(256) void gemm64_k(
    const unsigned short* __restrict__ A,
    const unsigned short* __restrict__ Bt,
    const float* __restrict__ bias,
    const float* __restrict__ bias2,
    const float* __restrict__ bias3,
    const int* __restrict__ cntS,
    const int* __restrict__ cntO,
    const int2* __restrict__ eidx,
    const unsigned short* __restrict__ gath,
    void* __restrict__ out0,
    int M, int K, int N, int ldT,
    long strideA, long strideB, long strideC)
{
  __shared__ __align__(16) unsigned short smem[BM*64 + BN*64];
  const int nxy = gridDim.x * gridDim.y;
  int bid = xcd_chunk(blockIdx.y * gridDim.x + blockIdx.x, nxy);
  const int m0 = (bid / gridDim.x) * BM;
  const int n0 = (bid % gridDim.x) * BN;
  const size_t zb = blockIdx.z;
  const unsigned short* Az  = A + zb * strideA;
  const unsigned short* Btz = Bt + zb * strideB;
  void* outz;
  if constexpr (MODE == 3) outz = (unsigned short*)out0 + zb * strideC;
  else if constexpr (MODE == 6 || MODE == 8) outz = (char*)out0 + zb * strideC * 4;
  else outz = (char*)out0 + zb * strideC * 2;
  gemm_core<MODE,BM,BN>(smem, smem + BM*64, Az, Btz, bias, bias2, bias3,
                        cntS, cntO, eidx, gath, outz, m0, n0, M, K, N, ldT);
}

// --- edges dtype autodetect ---
__global__ __launch_bounds__(256) void detect_k(const int* __restrict__ e, int* __restrict__ flag)
{
  const int i = blockIdx.x * 256 + threadIdx.x;
  if (i >= NTRI) return;
  if (e[2*i + 1] != 0) atomicOr(flag, 1);   // any nonzero odd word => int32 layout
}

__global__ __launch_bounds__(256) void norm_k(const int* __restrict__ e, const int* __restrict__ flag,
                                              int2* __restrict__ eidx)
{
  const int i = blockIdx.x * 256 + threadIdx.x;
  if (i >= NTRI) return;
  int s, o;
  if (*flag){ s = e[2*i]; o = e[2*i + 1]; }
  else      { s = e[4*i]; o = e[4*i + 2]; }
  s = min(max(s, 0), NOBJ - 1);
  o = min(max(o, 0), NOBJ - 1);
  eidx[i] = make_int2(s, o);
}

__global__ __launch_bounds__(256) void deg_k(const int2* __restrict__ eidx,
                                             int* __restrict__ cnt_s, int* __restrict__ cnt_o)
{
  const int i = blockIdx.x * 256 + threadIdx.x;
  if (i >= NTRI) return;
  atomicAdd(&cnt_s[eidx[i].x], 1);
  atomicAdd(&cnt_o[eidx[i].y], 1);
}

__global__ __launch_bounds__(1024) void scan_k(const int* __restrict__ cnt_s,
                                               const int* __restrict__ cnt_o,
                                               int* __restrict__ offs)
{
  __shared__ int sd[1024];
  __shared__ int carry;
  if (threadIdx.x == 0) carry = 0;
  __syncthreads();
  const int nIter = (NOBJ + 1023) / 1024;
  for (int it = 0; it < nIter; ++it){
    const int i = it * 1024 + (int)threadIdx.x;
    const int v = (i < NOBJ) ? (cnt_s[i] + cnt_o[i]) : 0;
    sd[threadIdx.x] = v;
    __syncthreads();
    for (int off = 1; off < 1024; off <<= 1){
      const int t = ((int)threadIdx.x >= off) ? sd[threadIdx.x - off] : 0;
      __syncthreads();
      sd[threadIdx.x] += t;
      __syncthreads();
    }
    if (i < NOBJ) offs[i] = carry + sd[threadIdx.x] - v;
    __syncthreads();
    if (threadIdx.x == 0){
      carry += sd[1023];
      if (it == nIter - 1) offs[NOBJ] = carry;
    }
    __syncthreads();
  }
}

// slot payload: (2*e+role, other_object_index)
__global__ __launch_bounds__(256) void fill_k(const int2* __restrict__ eidx,
                                              int* __restrict__ cursor, int2* __restrict__ slots)
{
  const int i = blockIdx.x * 256 + threadIdx.x;
  if (i >= NTRI) return;
  const int2 e = eidx[i];
  slots[atomicAdd(&cursor[e.x], 1)] = make_int2(2*i,     e.y);   // subject role
  slots[atomicAdd(&cursor[e.y], 1)] = make_int2(2*i + 1, e.x);   // object role
}

// tSO[o][1536] = [ns*obj[o] | SUMs pred | SUMs obj[oidx] | SUMo obj[sidx] | SUMo pred | no*obj[o]]
// ushort4 loads (8B/lane), 4 slot-groups in parallel, LDS tree-combine.
__device__ __forceinline__ void pool_core(
    const unsigned short* __restrict__ obj, const unsigned short* __restrict__ pred,
    const int* __restrict__ offs, const int2* __restrict__ slots,
    const int* __restrict__ cnt_s, const int* __restrict__ cnt_o,
    unsigned short* __restrict__ tSO, int o, float (*red)[4][256])
{
  const int tid  = (int)threadIdx.x;
  const int g    = tid >> 6;
  const int lane = tid & 63;
  const int c4   = lane << 2;
  const int b0 = offs[o], b1 = offs[o + 1];
  float sp0=0.f, sp1=0.f, sp2=0.f, sp3=0.f;
  float so0=0.f, so1=0.f, so2=0.f, so3=0.f;
  float oo0=0.f, oo1=0.f, oo2=0.f, oo3=0.f;
  float op0=0.f, op1=0.f, op2=0.f, op3=0.f;
  for (int j = b0 + g; j < b1; j += 4){
    const int2 sl = slots[j];
    const ushort4 pv = *(const ushort4*)(pred + (size_t)(sl.x >> 1) * DD + c4);
    const ushort4 ov = *(const ushort4*)(obj  + (size_t)sl.y * DD + c4);
    const float p0 = bf2f(pv.x), p1 = bf2f(pv.y), p2 = bf2f(pv.z), p3 = bf2f(pv.w);
    const float q0 = bf2f(ov.x), q1 = bf2f(ov.y), q2 = bf2f(ov.z), q3 = bf2f(ov.w);
    if (sl.x & 1){ op0+=p0; op1+=p1; op2+=p2; op3+=p3; oo0+=q0; oo1+=q1; oo2+=q2; oo3+=q3; }
    else         { sp0+=p0; sp1+=p1; sp2+=p2; sp3+=p3; so0+=q0; so1+=q1; so2+=q2; so3+=q3; }
  }
  red[g][0][c4+0]=sp0; red[g][0][c4+1]=sp1; red[g][0][c4+2]=sp2; red[g][0][c4+3]=sp3;
  red[g][1][c4+0]=so0; red[g][1][c4+1]=so1; red[g][1][c4+2]=so2; red[g][1][c4+3]=so3;
  red[g][2][c4+0]=oo0; red[g][2][c4+1]=oo1; red[g][2][c4+2]=oo2; red[g][2][c4+3]=oo3;
  red[g][3][c4+0]=op0; red[g][3][c4+1]=op1; red[g][3][c4+2]=op2; red[g][3][c4+3]=op3;
  __syncthreads();
  unsigned short* dst = tSO + (size_t)o * 1536;
#define TOTW(s, off) { \
    const float4 t0 = *(const float4*)&red[0][s][c4]; \
    const float4 t1 = *(const float4*)&red[1][s][c4]; \
    const float4 t2 = *(const float4*)&red[2][s][c4]; \
    const float4 t3 = *(const float4*)&red[3][s][c4]; \
    ushort4 w; \
    w.x = f2bf(t0.x + t1.x + t2.x + t3.x); \
    w.y = f2bf(t0.y + t1.y + t2.y + t3.y); \
    w.z = f2bf(t0.z + t1.z + t2.z + t3.z); \
    w.w = f2bf(t0.w + t1.w + t2.w + t3.w); \
    *(ushort4*)(dst + (off) + c4) = w; }
  if (g == 0){
    const ushort4 ob = *(const ushort4*)(obj + (size_t)o * DD + c4);
    const float ns = (float)cnt_s[o];
    ushort4 w;
    w.x = f2bf(ns * bf2f(ob.x)); w.y = f2bf(ns * bf2f(ob.y));
    w.z = f2bf(ns * bf2f(ob.z)); w.w = f2bf(ns * bf2f(ob.w));
    *(ushort4*)(dst + c4) = w;
    TOTW(0, 256);
  } else if (g == 1){
    TOTW(1, 512);
  } else if (g == 2){
    TOTW(2, 768);
    const ushort4 ob = *(const ushort4*)(obj + (size_t)o * DD + c4);
    const float no = (float)cnt_o[o];
    ushort4 w;
    w.x = f2bf(no * bf2f(ob.x)); w.y = f2bf(no * bf2f(ob.y));
    w.z = f2bf(no * bf2f(ob.z)); w.w = f2bf(no * bf2f(ob.w));
    *(ushort4*)(dst + 1280 + c4) = w;
  } else {
    TOTW(3, 1024);
  }
#undef TOTW
}

__global__ __launch_bounds__(256) void pool_t_k(
    const unsigned short* __restrict__ obj, const unsigned short* __restrict__ pred,
    const int* __restrict__ offs, const int2* __restrict__ slots,
    const int* __restrict__ cnt_s, const int* __restrict__ cnt_o,
    unsigned short* __restrict__ tSO)
{
  __shared__ __align__(16) float red[4][4][256];
  pool_core(obj, pred, offs, slots, cnt_s, cnt_o, tSO, blockIdx.x, red);
}

// L1 fused: pool_t (blocks [0,NOBJ)) || GEMM_C objSO = obj @ WpSO (128x64 tile)
__global__ __launch_bounds__(256) void fusedPC_k(
    const unsigned short* __restrict__ obj, const unsigned short* __restrict__ pred,
    const int* __restrict__ offs, const int2* __restrict__ slots,
    const int* __restrict__ cnt_s, const int* __restrict__ cnt_o,
    unsigned short* __restrict__ tSO,
    const unsigned short* __restrict__ WpSOT, unsigned short* __restrict__ objSO)
{
  __shared__ __align__(16) char smem[24576];   // max(pool 16KB, gemm 24KB)
  int b = blockIdx.x;
  if (b < NOBJ){
    pool_core(obj, pred, offs, slots, cnt_s, cnt_o, tSO, b, (float (*)[4][256])smem);
  } else {
    constexpr int GXC = HH / 64;                       // 8
    const int NC = GXC * ((NOBJ + 127) / 128);         // 1256
    b = xcd_chunk(b - NOBJ, NC);
    const int m0 = (b / GXC) * 128, n0 = (b % GXC) * 64;
    gemm_core<5,128,64>((unsigned short*)smem, (unsigned short*)smem + 128*64,
        obj, WpSOT, nullptr, nullptr, nullptr, nullptr, nullptr, nullptr, nullptr,
        objSO, m0, n0, NOBJ, 256, HH, 0);
  }
}

// L2 fused: GEMM_A (blocks [0,NA)) || GEMM_B (fused epilogue), both 128x64.
template<int MA, int MB>
__global__ __launch_bounds__(256) void fusedAB_k(
    const unsigned short* __restrict__ tSO, const unsigned short* __restrict__ WWTl,
    const float* __restrict__ c1p, const float* __restrict__ c2p,
    const float* __restrict__ b34c,
    const int* __restrict__ cnt_s, const int* __restrict__ cnt_o,
    void* __restrict__ outA,
    const unsigned short* __restrict__ predc, const unsigned short* __restrict__ WpPTl,
    const float* __restrict__ biasB, const int2* __restrict__ eidx,
    const unsigned short* __restrict__ objSO, void* __restrict__ outB)
{
  __shared__ __align__(16) unsigned short smem[128*64 + 64*64];
  constexpr int GX = DD / 64;                          // 4
  const int NA = GX * ((NOBJ + 127) / 128);            // 628
  int b = blockIdx.x;
  if (b < NA){
    b = xcd_chunk(b, NA);
    const int m0 = (b / GX) * 128, n0 = (b % GX) * 64;
    gemm_core<MA,128,64>(smem, smem + 128*64, tSO, WWTl, c1p, c2p, b34c,
        cnt_s, cnt_o, nullptr, nullptr, outA, m0, n0, NOBJ, 1536, DD, 0);
  } else {
    const int NB = GX * ((NTRI + 127) / 128);          // 1876
    b = xcd_chunk(b - NA, NB);
    const int m0 = (b / GX) * 128, n0 = (b % GX) * 64;
    gemm_core<MB,128,64>(smem, smem + 128*64, predc, WpPTl, biasB, nullptr, nullptr,
        nullptr, nullptr, eidx, objSO, outB, m0, n0, NTRI, 256, DD, 0);
  }
}

// fallback path only: new_pred[e][c] = predP[e][c] + objSO[s_e][c] + objSO[o_e][256+c]
template<int OUT>
__global__ __launch_bounds__(256) void add_k(
    const unsigned short* __restrict__ predP, const unsigned short* __restrict__ objSO,
    const int2* __restrict__ eidx, void* __restrict__ outp)
{
  const int i = blockIdx.x * 256 + threadIdx.x;
  if (i >= NTRI * 64) return;
  const int e  = i >> 6;
  const int c4 = (i & 63) << 2;
  const int2 ei = eidx[e];
  const ushort4 a = *(const ushort4*)(predP + (size_t)e * DD + c4);
  const ushort4 s = *(const ushort4*)(objSO + (size_t)ei.x * 512 + c4);
  const ushort4 o = *(const ushort4*)(objSO + (size_t)ei.y * 512 + 256 + c4);
  float v0 = bf2f(a.x) + bf2f(s.x) + bf2f(o.x);
  float v1 = bf2f(a.y) + bf2f(s.y) + bf2f(o.y);
  float v2 = bf2f(a.z) + bf2f(s.z) + bf2f(o.z);
  float v3 = bf2f(a.w) + bf2f(s.w) + bf2f(o.w);
  if constexpr (OUT){
    float4 r = make_float4(v0, v1, v2, v3);
    *(float4*)((float*)outp + (size_t)e * DD + c4) = r;
  } else {
    ushort4 r;
    r.x = f2bf(v0); r.y = f2bf(v1); r.z = f2bf(v2); r.w = f2bf(v3);
    *(ushort4*)((unsigned short*)outp + (size_t)e * DD + c4) = r;
  }
}

// fp32 -> bf16 flat (vector x4)
__global__ __launch_bounds__(256) void conv_f2b_k(const float* __restrict__ x,
                                                  unsigned short* __restrict__ y, int n4)
{
  const int i = blockIdx.x * 256 + threadIdx.x;
  if (i >= n4) return;
  const float4 v = ((const float4*)x)[i];
  ushort4 r;
  r.x = f2bf(v.x); r.y = f2bf(v.y); r.z = f2bf(v.z); r.w = f2bf(v.w);
  ((ushort4*)y)[i] = r;
}

// batched (L=5) transpose-convert: Wt[l][n][k] = bf16(W[l][k][colOff+n]), K=512
__global__ __launch_bounds__(256) void conv_wT_k(
    const float* __restrict__ W, unsigned short* __restrict__ Wt,
    int N, int ldW, int colOff, long wLS, long oLS)
{
  const int idx = blockIdx.x * 256 + threadIdx.x;
  const int per = N * 512;
  if (idx >= 5 * per) return;
  const int l = idx / per;
  const int r = idx - l * per;
  const int n = r >> 9;
  const int k = r & 511;
  Wt[l * oLS + (size_t)n * 512 + k] = f2bf(W[l * wLS + (size_t)k * ldW + colOff + n]);
}

// cb2[l][0..1280) = b1[l]@W2[l] + b2[l];  b34c[l][0..256) = b3[l]@W4[l] + b4[l]
__global__ __launch_bounds__(256) void biascomp_k(
    const float* __restrict__ b1, const float* __restrict__ W2, const float* __restrict__ b2,
    const float* __restrict__ b3, const float* __restrict__ W4, const float* __restrict__ b4,
    float* __restrict__ cb2, float* __restrict__ b34c)
{
  const int idx = blockIdx.x * 256 + threadIdx.x;
  if (idx < 5 * 1280){
    const int l = idx / 1280, n = idx - l * 1280;
    float s = b2[l * 1280 + n];
    for (int k = 0; k < 512; ++k)
      s += b1[l * 512 + k] * W2[(size_t)l * 512 * 1280 + (size_t)k * 1280 + n];
    cb2[idx] = s;
  } else if (idx < 5 * 1280 + 5 * 256){
    const int j = idx - 6400;
    const int l = j / 256, n = j - l * 256;
    float s = b4[l * 256 + n];
    for (int k = 0; k < 512; ++k)
      s += b3[l * 512 + k] * W4[(size_t)l * 512 * 256 + (size_t)k * 256 + n];
    b34c[j] = s;
  }
}

// c1p[l][n] = c1[l]@W34c[l][:,n],  c2p[l][n] = c2[l]@W34c[l][:,n]   (W34T bf16 [l][n][k])
__global__ __launch_bounds__(256) void compose_c_k(
    const float* __restrict__ cb2, const unsigned short* __restrict__ W34T,
    float* __restrict__ c1p, float* __restrict__ c2p)
{
  const int idx = blockIdx.x * 256 + threadIdx.x;
  if (idx >= 5 * 256) return;
  const int l = idx >> 8, n = idx & 255;
  const unsigned short* wr = W34T + ((size_t)l * 256 + n) * 512;
  float a = 0.f, b = 0.f;
  for (int k = 0; k < 512; ++k){
    const float w = bf2f(wr[k]);
    a += cb2[l * 1280 + k] * w;
    b += cb2[l * 1280 + 768 + k] * w;
  }
  c1p[idx] = a;
  c2p[idx] = b;
}

extern "C" void kernel_launch(void* const* d_in, const int* in_sizes, int n_in,
                              void* d_out, int out_size, void* d_ws, size_t ws_size,
                              hipStream_t stream)
{
  const float* obj_in  = (const float*)d_in[0];
  const float* pred_in = (const float*)d_in[1];
  const int*   edges   = (const int*)d_in[2];
  const float* W1 = (const float*)d_in[3];
  const float* b1 = (const float*)d_in[4];
  const float* W2 = (const float*)d_in[5];
  const float* b2 = (const float*)d_in[6];
  const float* W3 = (const float*)d_in[7];
  const float* b3 = (const float*)d_in[8];
  const float* W4 = (const float*)d_in[9];
  const float* b4 = (const float*)d_in[10];
  float* out = (float*)d_out;

  char* p = (char*)d_ws;
  auto alloc = [&](size_t bytes){ char* r = p; p += (bytes + 255) & ~(size_t)255; return r; };

  // weight staging (bf16) — DEAD after preamble; objSO overlays this region
  // (22.3MB contiguous W1bf..Wso_rm >= 20.5MB) during the layer loop.
  unsigned short* W1bf  = (unsigned short*)alloc((size_t)5 * 768 * 512 * 2);
  unsigned short* W2pT  = (unsigned short*)alloc((size_t)5 * 256 * 512 * 2);
  unsigned short* W2sT  = (unsigned short*)alloc((size_t)5 * 512 * 512 * 2);
  unsigned short* W2oT  = (unsigned short*)alloc((size_t)5 * 512 * 512 * 2);
  unsigned short* W3bf  = (unsigned short*)alloc((size_t)5 * 512 * 512 * 2);
  unsigned short* W4T   = (unsigned short*)alloc((size_t)5 * 256 * 512 * 2);
  unsigned short* Wso_rm = (unsigned short*)alloc((size_t)5 * 1536 * 512 * 2); // W1@[W2s;W2o]
  // composed weights (LIVE through layers)
  unsigned short* W34T   = (unsigned short*)alloc((size_t)5 * 256 * 512 * 2);  // (W3@W4)^T (preamble only)
  unsigned short* WWT    = (unsigned short*)alloc((size_t)5 * 256 * 1536 * 2); // (Wso@W34)^T
  unsigned short* WpSOT  = (unsigned short*)alloc((size_t)5 * 512 * 256 * 2);  // [Wp_s|Wp_o]^T
  unsigned short* WpPT   = (unsigned short*)alloc((size_t)5 * 256 * 256 * 2);  // Wp_p^T
  float* cb2  = (float*)alloc((size_t)5 * 1280 * 4);
  float* b34c = (float*)alloc((size_t)5 * 256 * 4);
  float* c1p  = (float*)alloc((size_t)5 * 256 * 4);
  float* c2p  = (float*)alloc((size_t)5 * 256 * 4);
  // activations
  unsigned short* objA    = (unsigned short*)alloc((size_t)NOBJ * DD * 2);   // 10.2 MB
  unsigned short* objB    = (unsigned short*)alloc((size_t)NOBJ * DD * 2);   // 10.2 MB
  unsigned short* pred_bf = (unsigned short*)alloc((size_t)NTRI * DD * 2);   // 30.7 MB
  unsigned short* tSO     = (unsigned short*)alloc((size_t)NOBJ * 1536 * 2); // 61.4 MB
  // fused path: objSO overlays dead preamble staging (NOT tSO)
  unsigned short* objSO_pre = W1bf;                               // 20.5 MB
  // fallback overlays into tSO (serial path only):
  unsigned short* objSO_fb = tSO;
  unsigned short* predP    = tSO + (size_t)NOBJ * 512;
  // CSR
  int2* eidx  = (int2*)alloc((size_t)NTRI * 8);
  int*  offs  = (int*)alloc((NOBJ + 1) * 4);
  int2* slots = (int2*)alloc((size_t)2 * NTRI * 8);
  int* cnt_s  = (int*)alloc(NOBJ * 4);
  int* cnt_o  = (int*)alloc(NOBJ * 4);
  int* cursor = (int*)alloc(NOBJ * 4);
  int* flag   = (int*)alloc(256);

  // pred double-buffer for the fused-epilogue path, only if workspace allows.
  unsigned short* predB = nullptr;
  {
    const size_t used = (size_t)(p - (char*)d_ws);
    if (ws_size >= used + (size_t)NTRI * DD * 2 + 512)
      predB = (unsigned short*)alloc((size_t)NTRI * DD * 2);
  }

  // ---- CSR preamble (edges are layer-invariant) ----
  (void)hipMemsetAsync(cnt_s, 0, NOBJ * 4, stream);
  (void)hipMemsetAsync(cnt_o, 0, NOBJ * 4, stream);
  (void)hipMemsetAsync(flag, 0, 4, stream);
  const int EB = (NTRI + 255) / 256;
  detect_k<<<EB, 256, 0, stream>>>(edges, flag);
  norm_k<<<EB, 256, 0, stream>>>(edges, flag, eidx);
  deg_k<<<EB, 256, 0, stream>>>(eidx, cnt_s, cnt_o);
  scan_k<<<1, 1024, 0, stream>>>(cnt_s, cnt_o, offs);
  (void)hipMemcpyAsync(cursor, offs, NOBJ * 4, hipMemcpyDeviceToDevice, stream);
  fill_k<<<EB, 256, 0, stream>>>(eidx, cursor, slots);

  // ---- inputs -> bf16 ----
  conv_f2b_k<<<(NOBJ * DD / 4 + 255) / 256, 256, 0, stream>>>(obj_in, objA, NOBJ * DD / 4);
  conv_f2b_k<<<(NTRI * DD / 4 + 255) / 256, 256, 0, stream>>>(pred_in, pred_bf, NTRI * DD / 4);

  // ---- weight staging ----
  conv_f2b_k<<<(5 * 768 * 512 / 4 + 255) / 256, 256, 0, stream>>>(W1, W1bf, 5 * 768 * 512 / 4);
  conv_f2b_k<<<(5 * 512 * 512 / 4 + 255) / 256, 256, 0, stream>>>(W3, W3bf, 5 * 512 * 512 / 4);
  conv_wT_k<<<(5 * 256 * 512 + 255) / 256, 256, 0, stream>>>(W2, W2pT, 256, 1280, 512, 512L*1280, 256L*512);
  conv_wT_k<<<(5 * 512 * 512 + 255) / 256, 256, 0, stream>>>(W2, W2sT, 512, 1280, 0,   512L*1280, 512L*512);
  conv_wT_k<<<(5 * 512 * 512 + 255) / 256, 256, 0, stream>>>(W2, W2oT, 512, 1280, 768, 512L*1280, 512L*512);
  conv_wT_k<<<(5 * 256 * 512 + 255) / 256, 256, 0, stream>>>(W4, W4T,  256, 256,  0,   512L*256,  256L*512);
  biascomp_k<<<30, 256, 0, stream>>>(b1, W2, b2, b3, W4, b4, cb2, b34c);

#define NP5 nullptr, nullptr, nullptr, nullptr, nullptr, nullptr, nullptr
  // ---- weight composition GEMMs (grid.z = 5 layers), 64x64 tiles ----
  gemm64_k<5,64,64><<<dim3(8, 12, 5), 256, 0, stream>>>(W1bf, W2sT, NP5,
      Wso_rm, 768, 512, 512, 0, 768L*512, 512L*512, 1536L*512);
  gemm64_k<5,64,64><<<dim3(8, 12, 5), 256, 0, stream>>>(W1bf, W2oT, NP5,
      Wso_rm + (size_t)768*512, 768, 512, 512, 0, 768L*512, 512L*512, 1536L*512);
  gemm64_k<3,64,64><<<dim3(4, 8, 5), 256, 0, stream>>>(W3bf, W4T, NP5,
      W34T, 512, 512, 256, 512, 512L*512, 256L*512, 256L*512);
  gemm64_k<3,64,64><<<dim3(4, 24, 5), 256, 0, stream>>>(Wso_rm, W34T, NP5,
      WWT, 1536, 512, 256, 1536, 1536L*512, 256L*512, 256L*1536);
  gemm64_k<3,64,64><<<dim3(4, 4, 5), 256, 0, stream>>>(W1bf, W2pT, NP5,
      WpSOT, 256, 512, 256, 256, 768L*512, 256L*512, 512L*256);
  gemm64_k<3,64,64><<<dim3(4, 4, 5), 256, 0, stream>>>(W1bf + (size_t)512*512, W2pT, NP5,
      WpSOT + (size_t)256*256, 256, 512, 256, 256, 768L*512, 256L*512, 512L*256);
  gemm64_k<3,64,64><<<dim3(4, 4, 5), 256, 0, stream>>>(W1bf + (size_t)256*512, W2pT, NP5,
      WpPT, 256, 512, 256, 256, 768L*512, 256L*512, 256L*256);
  compose_c_k<<<5, 256, 0, stream>>>(cb2, W34T, c1p, c2p);

  // ---- layers ----
  unsigned short* objbuf[2]  = { objA, objB };
  unsigned short* predbuf[2] = { pred_bf, predB };
  int cur = 0, pc = 0;
  const int NPC = NOBJ + 8 * ((NOBJ + 127) / 128);          // 20000 + 1256
  const int NAB = 4 * ((NOBJ + 127) / 128) + 4 * ((NTRI + 127) / 128);  // 628 + 1876
  for (int l = 0; l < 5; ++l){
    const unsigned short* objc  = objbuf[cur];
    const unsigned short* predc = predbuf[pc];
    if (predB){
      // L1: pool_t || GEMM_C  (objSO in dead preamble region; no tSO conflict)
      fusedPC_k<<<NPC, 256, 0, stream>>>(objc, predc, offs, slots, cnt_s, cnt_o,
          tSO, WpSOT + (size_t)l*512*256, objSO_pre);
      // L2: GEMM_A || GEMM_B(fused gather epilogue)
      if (l < 4)
        fusedAB_k<2,7><<<NAB, 256, 0, stream>>>(tSO, WWT + (size_t)l*256*1536,
            c1p + l*256, c2p + l*256, b34c + l*256, cnt_s, cnt_o, objbuf[cur ^ 1],
            predc, WpPT + (size_t)l*256*256, cb2 + (size_t)l*1280 + 512, eidx,
            objSO_pre, predbuf[pc ^ 1]);
      else
        fusedAB_k<6,8><<<NAB, 256, 0, stream>>>(tSO, WWT + (size_t)l*256*1536,
            c1p + l*256, c2p + l*256, b34c + l*256, cnt_s, cnt_o, out,
            predc, WpPT + (size_t)l*256*256, cb2 + (size_t)l*1280 + 512, eidx,
            objSO_pre, out + (size_t)NOBJ * DD);
      pc ^= 1;
    } else {
      // fallback: serial launches, objSO overlays tSO, predP + add_k
      pool_t_k<<<NOBJ, 256, 0, stream>>>(objc, predc, offs, slots, cnt_s, cnt_o, tSO);
      const int GY_OBJ = (NOBJ + 127) / 128;
      const int GY_TRI = (NTRI + 127) / 128;
      if (l < 4)
        gemm64_k<2,128,64><<<dim3(4, GY_OBJ), 256, 0, stream>>>(tSO, WWT + (size_t)l*256*1536,
            c1p + l*256, c2p + l*256, b34c + l*256, cnt_s, cnt_o, nullptr, nullptr,
            objbuf[cur ^ 1], NOBJ, 1536, DD, 0, 0, 0, 0);
      else
        gemm64_k<6,128,64><<<dim3(4, GY_OBJ), 256, 0, stream>>>(tSO, WWT + (size_t)l*256*1536,
            c1p + l*256, c2p + l*256, b34c + l*256, cnt_s, cnt_o, nullptr, nullptr,
            out, NOBJ, 1536, DD, 0, 0, 0, 0);
      gemm64_k<5,128,64><<<dim3(8, GY_OBJ), 256, 0, stream>>>(objc, WpSOT + (size_t)l*512*256,
          NP5, objSO_fb, NOBJ, 256, 512, 0, 0, 0, 0);
      gemm64_k<0,128,64><<<dim3(4, GY_TRI), 256, 0, stream>>>(predc, WpPT + (size_t)l*256*256,
          cb2 + (size_t)l*1280 + 512, nullptr, nullptr, nullptr, nullptr, nullptr, nullptr,
          predP, NTRI, 256, DD, 0, 0, 0, 0);
      if (l < 4)
        add_k<0><<<(NTRI * 64 + 255) / 256, 256, 0, stream>>>(predP, objSO_fb, eidx, pred_bf);
      else
        add_k<1><<<(NTRI * 64 + 255) / 256, 256, 0, stream>>>(predP, objSO_fb, eidx, out + (size_t)NOBJ * DD);
    }
    cur ^= 1;
  }
#undef NP5
}